// Round 1
// baseline (145.458 us; speedup 1.0000x reference)
//
#include <hip/hip_runtime.h>
#include <math.h>

#define EPS 1e-8f
#define TWOPI 6.2831853071795864769f

// ws layout (float offsets)
#define WS_WMAX 0        // 50
#define WS_WN   64       // 50*16 = 800
#define WS_C1   1024     // 50*50*2 = 5000   c1[m][i] = exp(-2pi i * k(m)*(75+i)/200)
#define WS_E2   6144     // 52*64*2 = 6656   e2[cc][j] = exp(-2pi i * (cc+1)*j/200)
#define WS_AMPA 12800    // 100*52 = 5200    |fft_sig_shift[50+s, 101+u]|
#define WS_AMPN 18048    // 50*50 = 2500     normalized pooled amp

// ---------------- batch-independent precompute ----------------
__global__ __launch_bounds__(256) void k_pre(const float* __restrict__ w,
                                             float* __restrict__ ws) {
    int t = threadIdx.x;
    if (t < 50) {
        float mx = 0.f;
        float vals[16];
        for (int q = 0; q < 16; ++q) {
            float v = fabsf(w[t * 16 + q]);
            vals[q] = v;
            mx = fmaxf(mx, v);
        }
        ws[WS_WMAX + t] = mx;
        float d = mx + EPS;
        for (int q = 0; q < 16; ++q) ws[WS_WN + t * 16 + q] = vals[q] / d;
    }
    // c1[m][i]: k(m) = (175+m)%200, phase = -(2pi/200) * ((k*(75+i)) % 200)
    for (int o = t; o < 2500; o += 256) {
        int m = o / 50, i = o - m * 50;
        int k = (175 + m) % 200;
        int ph = (k * (75 + i)) % 200;
        float s, c;
        sincosf(-TWOPI * (float)ph / 200.f, &s, &c);
        ws[WS_C1 + 2 * o] = c;
        ws[WS_C1 + 2 * o + 1] = s;
    }
    // e2[cc][j]: phase = -(2pi/200) * (((cc+1)*j) % 200)
    for (int o = t; o < 52 * 64; o += 256) {
        int cc = o >> 6, j = o & 63;
        int ph = ((cc + 1) * j) % 200;
        float s, c;
        sincosf(-TWOPI * (float)ph / 200.f, &s, &c);
        ws[WS_E2 + 2 * o] = c;
        ws[WS_E2 + 2 * o + 1] = s;
    }
}

// |fftshift(fft(full_sig, axis=0))| at rows 50..149, cols 101..152
__global__ __launch_bounds__(256) void k_ampabs(const float* __restrict__ fs,
                                                float* __restrict__ ws) {
    __shared__ float tc[200], tsn[200];
    int t = threadIdx.x;
    for (int i = t; i < 200; i += 256) {
        float s, c;
        sincosf(-TWOPI * (float)i / 200.f, &s, &c);
        tc[i] = c;
        tsn[i] = s;
    }
    __syncthreads();
    int o = blockIdx.x * 256 + t;
    if (o >= 5200) return;
    int s_ = o / 52, u = o - s_ * 52;
    int k = (150 + s_) % 200;   // (r'+100)%200 with r' = 50+s
    int j = 101 + u;
    float aR = 0.f, aI = 0.f;
    int ph = 0;
    for (int r = 0; r < 200; ++r) {
        float v = fs[r * 200 + j];
        aR += v * tc[ph];
        aI += v * tsn[ph];
        ph += k;
        if (ph >= 200) ph -= 200;
    }
    ws[WS_AMPA + o] = sqrtf(aR * aR + aI * aI);
}

// maxpool(2x3, stride 2x1) over [100,52] -> [50,50], normalize by max
__global__ __launch_bounds__(256) void k_amppool(float* __restrict__ ws) {
    __shared__ float ap[2500];
    __shared__ float red[256];
    int t = threadIdx.x;
    const float* aa = ws + WS_AMPA;
    float local = 0.f;
    for (int o = t; o < 2500; o += 256) {
        int h = o / 50, w = o - h * 50;
        float v = 0.f;
        for (int ds = 0; ds < 2; ++ds)
            for (int du = 0; du < 3; ++du)
                v = fmaxf(v, aa[(2 * h + ds) * 52 + w + du]);
        ap[o] = v;
        local = fmaxf(local, v);
    }
    red[t] = local;
    __syncthreads();
    for (int s = 128; s > 0; s >>= 1) {
        if (t < s) red[t] = fmaxf(red[t], red[t + s]);
        __syncthreads();
    }
    float mx = red[0] + EPS;
    for (int o = t; o < 2500; o += 256) ws[WS_AMPN + o] = ap[o] / mx;
}

// ---------------- main batched kernel: one block per batch ----------------
__global__ __launch_bounds__(256) void k_main(const float* __restrict__ in,
                                              const float* __restrict__ bias,
                                              const float* __restrict__ fs,
                                              const float* __restrict__ ws,
                                              float* __restrict__ out) {
    __shared__ float xpat[50][16];
    __shared__ float imax_s[50];
    __shared__ float T[49][64];       // full_sig[75+i,j] * inpn[i, j>>2]
    __shared__ float opcR[50][64];
    __shared__ float opcI[50][64];
    __shared__ float absG[50][52];
    __shared__ float res_s[26][50];   // pooled/amp, rows h=12..37
    __shared__ float red[256];

    const int t = threadIdx.x;
    const int b = blockIdx.x;
    const float* ib = in + b * 784;

    // phase 1: patches + row max + (row 49 zero)
    if (t < 50) {
        float mx = 0.f;
        if (t < 49) {
            int pr = t / 7, pc = t - pr * 7;
            for (int q = 0; q < 16; ++q) {
                float v = ib[(pr * 4 + (q >> 2)) * 28 + pc * 4 + (q & 3)];
                xpat[t][q] = v;
                mx = fmaxf(mx, v);
            }
        } else {
            for (int q = 0; q < 16; ++q) xpat[t][q] = 0.f;
        }
        imax_s[t] = mx;
    }
    __syncthreads();

    // phase 1b: T[i][j] = fs[75+i][j] * inpn[i][j>>2]
    for (int o = t; o < 49 * 64; o += 256) {
        int i = o >> 6, j = o & 63;
        T[i][j] = fs[(75 + i) * 200 + j] * (xpat[i][j >> 2] / (imax_s[i] + EPS));
    }
    __syncthreads();

    // phase 2: opc[m][j] = (sum_i c1[m][i] * T[i][j]) * wn[m][j>>2]
    const float* c1 = ws + WS_C1;
    const float* wn = ws + WS_WN;
    for (int o = t; o < 3200; o += 256) {
        int m = o >> 6, j = o & 63;
        float aR = 0.f, aI = 0.f;
        const float* cm = c1 + m * 100;
        for (int i = 0; i < 49; ++i) {
            float tv = T[i][j];
            aR += cm[2 * i] * tv;
            aI += cm[2 * i + 1] * tv;
        }
        float wv = wn[m * 16 + (j >> 2)];
        opcR[m][j] = aR * wv;
        opcI[m][j] = aI * wv;
    }
    __syncthreads();

    // phase 3: G[m][cc] = sum_j opc[m][j] * e2[cc][j];  absG = |G|
    const float* e2 = ws + WS_E2;
    for (int o = t; o < 2600; o += 256) {
        int m = o / 52, cc = o - m * 52;
        float aR = 0.f, aI = 0.f;
        const float* ec = e2 + cc * 128;
        for (int j = 0; j < 64; ++j) {
            float orr = opcR[m][j], oii = opcI[m][j];
            float er = ec[2 * j], ei = ec[2 * j + 1];
            aR += orr * er - oii * ei;
            aI += orr * ei + oii * er;
        }
        absG[m][cc] = sqrtf(aR * aR + aI * aI);
    }
    __syncthreads();

    // phase 4: pool (2x3 / 2x1), divide by amp_n, track batch max
    const float* ampn = ws + WS_AMPN;
    float local = 0.f;
    for (int o = t; o < 1300; o += 256) {
        int hh = o / 50, w = o - hh * 50;
        int h = hh + 12;
        int m1 = 2 * h - 25, m2 = 2 * h - 24;
        float v = 0.f;
        for (int du = 0; du < 3; ++du) {
            int u = w + du;
            if (m1 >= 0) v = fmaxf(v, absG[m1][u]);
            if (m2 < 50) v = fmaxf(v, absG[m2][u]);
        }
        float r = v / ampn[h * 50 + w];
        res_s[hh][w] = r;
        local = fmaxf(local, r);
    }
    red[t] = local;
    __syncthreads();
    for (int s = 128; s > 0; s >>= 1) {
        if (t < s) red[t] = fmaxf(red[t], red[t + s]);
        __syncthreads();
    }
    float mres = red[0] + EPS;

    // phase 5: out[b,r,c] = bias[r,c] + res[c,r]/mres * imax[r]*wmax[c]
    const float* wmax = ws + WS_WMAX;
    for (int o = t; o < 2450; o += 256) {
        int r = o / 50, c = o - r * 50;
        float val = bias[o];
        if (c >= 12 && c < 38) {
            val += (res_s[c - 12][r] / mres) * imax_s[r] * wmax[c];
        }
        out[b * 2450 + o] = val;
    }
}

extern "C" void kernel_launch(void* const* d_in, const int* in_sizes, int n_in,
                              void* d_out, int out_size, void* d_ws, size_t ws_size,
                              hipStream_t stream) {
    const float* in   = (const float*)d_in[0];   // [512,1,28,28]
    const float* w    = (const float*)d_in[1];   // [50,16]
    const float* bias = (const float*)d_in[2];   // [1,49,50]
    const float* fs   = (const float*)d_in[3];   // [200,200]
    float* out = (float*)d_out;                  // [512,49,50] f32
    float* ws  = (float*)d_ws;

    hipLaunchKernelGGL(k_pre,     dim3(1),   dim3(256), 0, stream, w, ws);
    hipLaunchKernelGGL(k_ampabs,  dim3(21),  dim3(256), 0, stream, fs, ws);
    hipLaunchKernelGGL(k_amppool, dim3(1),   dim3(256), 0, stream, ws);
    hipLaunchKernelGGL(k_main,    dim3(512), dim3(256), 0, stream, in, bias, fs, ws, out);
}

// Round 2
// 58.703 us; speedup vs baseline: 2.4779x; 2.4779x over previous
//
#include <hip/hip_runtime.h>
#include <math.h>

#define EPS 1e-8f
#define TWOPI 6.2831853071795864769f

// ws layout (float offsets)
#define WS_WMAX 0        // 50
#define WS_WN   64       // 50*16 = 800
#define WS_C1   1024     // 50*50*2 = 5000   float2 c1[m][i]
#define WS_E2T  6144     // 64*52*2 = 6656   float2 e2t[j][cc] (transposed)
#define WS_AMPA 12800    // 100*52 = 5200
#define WS_AMPN 18048    // 50*50 = 2500

// ---------------- batch-independent precompute ----------------
__global__ __launch_bounds__(256) void k_pre(const float* __restrict__ w,
                                             float* __restrict__ ws) {
    int gid = blockIdx.x * 256 + threadIdx.x;   // 8 blocks -> 2048 threads
    if (gid < 50) {
        float mx = 0.f;
        float vals[16];
        for (int q = 0; q < 16; ++q) {
            float v = fabsf(w[gid * 16 + q]);
            vals[q] = v;
            mx = fmaxf(mx, v);
        }
        ws[WS_WMAX + gid] = mx;
        float d = mx + EPS;
        for (int q = 0; q < 16; ++q) ws[WS_WN + gid * 16 + q] = vals[q] / d;
    }
    // c1[m][i]: k(m) = (175+m)%200, phase = -(2pi/200)*((k*(75+i))%200)
    for (int o = gid; o < 2500; o += 2048) {
        int m = o / 50, i = o - m * 50;
        int k = (175 + m) % 200;
        int ph = (k * (75 + i)) % 200;
        float s, c;
        sincosf(-TWOPI * (float)ph / 200.f, &s, &c);
        ws[WS_C1 + 2 * o] = c;
        ws[WS_C1 + 2 * o + 1] = s;
    }
    // e2t[j][cc]: phase = -(2pi/200)*(((cc+1)*j)%200)   (transposed layout)
    for (int o = gid; o < 64 * 52; o += 2048) {
        int j = o / 52, cc = o - j * 52;
        int ph = ((cc + 1) * j) % 200;
        float s, c;
        sincosf(-TWOPI * (float)ph / 200.f, &s, &c);
        ws[WS_E2T + 2 * o] = c;
        ws[WS_E2T + 2 * o + 1] = s;
    }
}

// |fftshift(fft(full_sig, axis=0))| at rows 50..149, cols 101..152
// 4-way split over r, quad shuffle reduction
__global__ __launch_bounds__(256) void k_ampabs(const float* __restrict__ fs,
                                                float* __restrict__ ws) {
    __shared__ float tc[200], tsn[200];
    int t = threadIdx.x;
    for (int i = t; i < 200; i += 256) {
        float s, c;
        sincosf(-TWOPI * (float)i / 200.f, &s, &c);
        tc[i] = c;
        tsn[i] = s;
    }
    __syncthreads();
    int gid = blockIdx.x * 256 + t;
    int q = gid >> 2, part = gid & 3;
    float aR = 0.f, aI = 0.f;
    int s_ = 0, u = 0;
    if (q < 5200) {
        s_ = q / 52;
        u = q - s_ * 52;
        int k = (150 + s_) % 200;
        int j = 101 + u;
        int ph = (k * (part * 50)) % 200;
        int r0 = part * 50;
        for (int r = r0; r < r0 + 50; ++r) {
            float v = fs[r * 200 + j];
            aR += v * tc[ph];
            aI += v * tsn[ph];
            ph += k;
            if (ph >= 200) ph -= 200;
        }
    }
    aR += __shfl_xor(aR, 1); aI += __shfl_xor(aI, 1);
    aR += __shfl_xor(aR, 2); aI += __shfl_xor(aI, 2);
    if (q < 5200 && part == 0) ws[WS_AMPA + q] = sqrtf(aR * aR + aI * aI);
}

// maxpool(2x3, stride 2x1) over [100,52] -> [50,50], normalize by max
__global__ __launch_bounds__(256) void k_amppool(float* __restrict__ ws) {
    __shared__ float ap[2500];
    __shared__ float red[256];
    int t = threadIdx.x;
    const float* aa = ws + WS_AMPA;
    float local = 0.f;
    for (int o = t; o < 2500; o += 256) {
        int h = o / 50, w = o - h * 50;
        float v = 0.f;
        for (int ds = 0; ds < 2; ++ds)
            for (int du = 0; du < 3; ++du)
                v = fmaxf(v, aa[(2 * h + ds) * 52 + w + du]);
        ap[o] = v;
        local = fmaxf(local, v);
    }
    red[t] = local;
    __syncthreads();
    for (int s = 128; s > 0; s >>= 1) {
        if (t < s) red[t] = fmaxf(red[t], red[t + s]);
        __syncthreads();
    }
    float mx = red[0] + EPS;
    for (int o = t; o < 2500; o += 256) ws[WS_AMPN + o] = ap[o] / mx;
}

// ---------------- main batched kernel: one block (512 thr) per batch ----------------
__global__ __launch_bounds__(512, 4) void k_main(const float* __restrict__ in,
                                                 const float* __restrict__ bias,
                                                 const float* __restrict__ fs,
                                                 const float* __restrict__ ws,
                                                 float* __restrict__ out) {
    __shared__ float2 c1s[50][50];    // 20000 B
    __shared__ float2 opc[50][64];    // 25600 B
    __shared__ float xpat[50][16];    // 3200 B
    __shared__ float imax_s[50];      // 200 B
    __shared__ float TB[3136];        // 12544 B; aliased: T[49][64] then absG[50*52]
    __shared__ float res_s[26][50];   // 5200 B
    __shared__ float red8[8];

    const int t = threadIdx.x;
    const int b = blockIdx.x;
    const int lane = t & 63;
    const int wid = t >> 6;           // 0..7, uniform per wave
    const float* ib = in + b * 784;

    // load c1 twiddles into LDS (float2, coalesced)
    {
        float2* dst = &c1s[0][0];
        const float2* src = (const float2*)(ws + WS_C1);
        for (int o = t; o < 2500; o += 512) dst[o] = src[o];
    }

    // phase 1: patches + row max
    if (t < 50) {
        float mx = 0.f;
        if (t < 49) {
            int pr = t / 7, pc = t - pr * 7;
            for (int q = 0; q < 16; ++q) {
                float v = ib[(pr * 4 + (q >> 2)) * 28 + pc * 4 + (q & 3)];
                xpat[t][q] = v;
                mx = fmaxf(mx, v);
            }
        }
        imax_s[t] = mx;
    }
    __syncthreads();

    // phase 1b: T[i][j] = fs[75+i][j] * inpn[i][j>>2]
    for (int o = t; o < 49 * 64; o += 512) {
        int i = o >> 6, j = o & 63;
        TB[o] = fs[(75 + i) * 200 + j] * (xpat[i][j >> 2] / (imax_s[i] + EPS));
    }
    __syncthreads();

    // phase 2: opc[m][j] = (sum_i c1[m][i]*T[i][j]) * wn[m][j>>2]
    // wave wid handles m = wid + 8k; lane = j. T read hoisted across the 7 m's.
    {
        const int nk = (wid < 2) ? 7 : 6;
        float aR[7], aI[7];
        #pragma unroll
        for (int k = 0; k < 7; ++k) { aR[k] = 0.f; aI[k] = 0.f; }
        for (int i = 0; i < 49; ++i) {
            float tv = TB[i * 64 + lane];
            #pragma unroll 7
            for (int k = 0; k < 7; ++k) {
                if (k < nk) {
                    float2 c = c1s[wid + 8 * k][i];   // broadcast ds_read_b64
                    aR[k] = fmaf(c.x, tv, aR[k]);
                    aI[k] = fmaf(c.y, tv, aI[k]);
                }
            }
        }
        const float* wn = ws + WS_WN;
        #pragma unroll 7
        for (int k = 0; k < 7; ++k) {
            if (k < nk) {
                int m = wid + 8 * k;
                float wv = wn[m * 16 + (lane >> 2)];
                opc[m][lane] = make_float2(aR[k] * wv, aI[k] * wv);
            }
        }
    }
    __syncthreads();

    // phase 3: G[m][cc] = sum_j opc[m][j]*e2t[j][cc]; absG (aliases TB) = |G|
    {
        const int nk = (wid < 2) ? 7 : 6;
        const int cc = lane;                       // active if cc < 52
        const float2* e2t = (const float2*)(ws + WS_E2T);  // [64][52]
        float bR[7], bI[7];
        #pragma unroll
        for (int k = 0; k < 7; ++k) { bR[k] = 0.f; bI[k] = 0.f; }
        for (int j = 0; j < 64; ++j) {
            float2 ev = (cc < 52) ? e2t[j * 52 + cc] : make_float2(0.f, 0.f);
            #pragma unroll 7
            for (int k = 0; k < 7; ++k) {
                if (k < nk) {
                    float2 ov = opc[wid + 8 * k][j];  // broadcast ds_read_b64
                    bR[k] = fmaf(ov.x, ev.x, bR[k]);
                    bR[k] = fmaf(-ov.y, ev.y, bR[k]);
                    bI[k] = fmaf(ov.x, ev.y, bI[k]);
                    bI[k] = fmaf(ov.y, ev.x, bI[k]);
                }
            }
        }
        if (cc < 52) {
            #pragma unroll 7
            for (int k = 0; k < 7; ++k) {
                if (k < nk) {
                    int m = wid + 8 * k;
                    TB[m * 52 + cc] = sqrtf(bR[k] * bR[k] + bI[k] * bI[k]);
                }
            }
        }
    }
    __syncthreads();

    // phase 4: pool (2x3 / 2x1), divide by amp_n, track batch max
    const float* ampn = ws + WS_AMPN;
    float local = 0.f;
    for (int o = t; o < 1300; o += 512) {
        int hh = o / 50, w = o - hh * 50;
        int h = hh + 12;
        int m1 = 2 * h - 25, m2 = 2 * h - 24;
        float v = 0.f;
        for (int du = 0; du < 3; ++du) {
            int u = w + du;
            if (m1 >= 0) v = fmaxf(v, TB[m1 * 52 + u]);
            if (m2 < 50) v = fmaxf(v, TB[m2 * 52 + u]);
        }
        float r = v / ampn[h * 50 + w];
        res_s[hh][w] = r;
        local = fmaxf(local, r);
    }
    // wave-level max reduce, then 8 partials
    #pragma unroll
    for (int off = 32; off > 0; off >>= 1)
        local = fmaxf(local, __shfl_xor(local, off));
    if (lane == 0) red8[wid] = local;
    __syncthreads();
    float mres = red8[0];
    #pragma unroll
    for (int i = 1; i < 8; ++i) mres = fmaxf(mres, red8[i]);
    mres += EPS;

    // phase 5: out[b,r,c] = bias[r,c] + res[c,r]/mres * imax[r]*wmax[c]
    const float* wmax = ws + WS_WMAX;
    for (int o = t; o < 2450; o += 512) {
        int r = o / 50, c = o - r * 50;
        float val = bias[o];
        if (c >= 12 && c < 38) {
            val += (res_s[c - 12][r] / mres) * imax_s[r] * wmax[c];
        }
        out[b * 2450 + o] = val;
    }
}

extern "C" void kernel_launch(void* const* d_in, const int* in_sizes, int n_in,
                              void* d_out, int out_size, void* d_ws, size_t ws_size,
                              hipStream_t stream) {
    const float* in   = (const float*)d_in[0];   // [512,1,28,28]
    const float* w    = (const float*)d_in[1];   // [50,16]
    const float* bias = (const float*)d_in[2];   // [1,49,50]
    const float* fs   = (const float*)d_in[3];   // [200,200]
    float* out = (float*)d_out;                  // [512,49,50] f32
    float* ws  = (float*)d_ws;

    hipLaunchKernelGGL(k_pre,     dim3(8),   dim3(256), 0, stream, w, ws);
    hipLaunchKernelGGL(k_ampabs,  dim3(82),  dim3(256), 0, stream, fs, ws);
    hipLaunchKernelGGL(k_amppool, dim3(1),   dim3(256), 0, stream, ws);
    hipLaunchKernelGGL(k_main,    dim3(512), dim3(512), 0, stream, in, bias, fs, ws, out);
}

// Round 3
// 50.742 us; speedup vs baseline: 2.8666x; 1.1569x over previous
//
#include <hip/hip_runtime.h>
#include <math.h>

#define EPS 1e-8f
#define TWOPI 6.2831853071795864769f

// ws layout (float offsets)
#define WS_WMAX 0        // 50
#define WS_WN   64       // 50*16
#define WS_C1   1024     // float2 c1[50][50]  (5000 floats)
#define WS_E2T  6144     // float2 e2t[64][52] (6656 floats)
#define WS_AMPA 12800    // float [100][52]    (5200 floats)

// ---------------- fused prologue: ampabs (blocks 0..81) + tables (82..89) ----
__global__ __launch_bounds__(256) void k_prelude(const float* __restrict__ w,
                                                 const float* __restrict__ fs,
                                                 float* __restrict__ ws) {
    const int blk = blockIdx.x, t = threadIdx.x;
    if (blk < 82) {
        // |fft(full_sig, axis=0)| at shifted rows 50..149, cols 101..152
        __shared__ float tc[200], tsn[200];
        for (int i = t; i < 200; i += 256) {
            float s, c;
            sincosf(-TWOPI * (float)i / 200.f, &s, &c);
            tc[i] = c; tsn[i] = s;
        }
        __syncthreads();
        int gid = blk * 256 + t;
        int q = gid >> 2, part = gid & 3;
        float aR = 0.f, aI = 0.f;
        if (q < 5200) {
            int s_ = q / 52, u = q - s_ * 52;
            int k = (150 + s_) % 200;
            int j = 101 + u;
            int ph = (k * (part * 50)) % 200;
            for (int r = part * 50; r < part * 50 + 50; ++r) {
                float v = fs[r * 200 + j];
                aR = fmaf(v, tc[ph], aR);
                aI = fmaf(v, tsn[ph], aI);
                ph += k; if (ph >= 200) ph -= 200;
            }
        }
        aR += __shfl_xor(aR, 1); aI += __shfl_xor(aI, 1);
        aR += __shfl_xor(aR, 2); aI += __shfl_xor(aI, 2);
        if (q < 5200 && part == 0) ws[WS_AMPA + q] = sqrtf(aR * aR + aI * aI);
    } else {
        int gid = (blk - 82) * 256 + t;   // 0..2047
        if (gid < 50) {
            float mx = 0.f, vals[16];
            for (int q = 0; q < 16; ++q) {
                float v = fabsf(w[gid * 16 + q]);
                vals[q] = v; mx = fmaxf(mx, v);
            }
            ws[WS_WMAX + gid] = mx;
            float d = mx + EPS;
            for (int q = 0; q < 16; ++q) ws[WS_WN + gid * 16 + q] = vals[q] / d;
        }
        // c1[m][i]: k(m)=(175+m)%200, phase = -(2pi/200)*((k*(75+i))%200)
        for (int o = gid; o < 2500; o += 2048) {
            int m = o / 50, i = o - m * 50;
            int k = (175 + m) % 200;
            int ph = (k * (75 + i)) % 200;
            float s, c;
            sincosf(-TWOPI * (float)ph / 200.f, &s, &c);
            ws[WS_C1 + 2 * o] = c; ws[WS_C1 + 2 * o + 1] = s;
        }
        // e2t[j][cc] (transposed): phase = -(2pi/200)*(((cc+1)*j)%200)
        for (int o = gid; o < 3328; o += 2048) {
            int j = o / 52, cc = o - j * 52;
            int ph = ((cc + 1) * j) % 200;
            float s, c;
            sincosf(-TWOPI * (float)ph / 200.f, &s, &c);
            ws[WS_E2T + 2 * o] = c; ws[WS_E2T + 2 * o + 1] = s;
        }
    }
}

// ---------------- main batched kernel: one block (512 thr) per batch --------
__global__ __launch_bounds__(512, 4) void k_main(const float* __restrict__ in,
                                                 const float* __restrict__ bias,
                                                 const float* __restrict__ fs,
                                                 const float* __restrict__ ws,
                                                 float* __restrict__ out) {
    __shared__ float2 opcs[50][64];   // 25600 B
    __shared__ float xpat[50][16];    // 3200 B
    __shared__ float imax_s[50];
    __shared__ float inv_s[50];
    __shared__ float TB[3136];        // T[49][64], then absG[50*52]
    __shared__ float res_s[26][50];   // 5200 B
    __shared__ float red8[8];

    const int t = threadIdx.x;
    const int b = blockIdx.x;
    const int lane = t & 63;
    const int wid = t >> 6;
    const int swid = __builtin_amdgcn_readfirstlane(wid);   // force SGPR
    const int M0 = swid * 6 + (swid < 2 ? swid : 2);        // contiguous m rows
    const int nk = 6 + (swid < 2 ? 1 : 0);                  // waves 0,1 take 7
    const float* ib = in + b * 784;

    // phase 1: patches (float4) + per-row max via quad shuffle
    if (t < 196) {
        int row = t >> 2, s4 = t & 3;
        int pr = row / 7, pc = row - pr * 7;
        float4 v4 = *(const float4*)(ib + (pr * 4 + s4) * 28 + pc * 4);
        *(float4*)(&xpat[row][s4 * 4]) = v4;
        float mx = fmaxf(fmaxf(v4.x, v4.y), fmaxf(v4.z, v4.w));
        mx = fmaxf(mx, __shfl_xor(mx, 1));
        mx = fmaxf(mx, __shfl_xor(mx, 2));
        if (s4 == 0) { imax_s[row] = mx; inv_s[row] = 1.f / (mx + EPS); }
    }
    __syncthreads();

    // phase 1b: T[i][j] = fs[75+i][j] * xpat[i][j>>2] * inv[i]
    for (int o = t; o < 3136; o += 512) {
        int i = o >> 6, j = o & 63;
        TB[o] = fs[(75 + i) * 200 + j] * xpat[i][j >> 2] * inv_s[i];
    }
    __syncthreads();

    // phase 2: opc[m][j] = (sum_i c1[m][i]*T[i][j]) * wn[m][j>>2]
    // c1 rows are wave-uniform -> scalar (s_load) path; T read once per i.
    {
        float aR[7], aI[7];
        #pragma unroll
        for (int k = 0; k < 7; ++k) { aR[k] = 0.f; aI[k] = 0.f; }
        const float* c1g = ws + WS_C1 + 100 * M0;
        #pragma unroll 2
        for (int i = 0; i < 49; ++i) {
            float tv = TB[i * 64 + lane];
            #pragma unroll
            for (int k = 0; k < 6; ++k) {
                float cR = c1g[k * 100 + 2 * i];
                float cI = c1g[k * 100 + 2 * i + 1];
                aR[k] = fmaf(cR, tv, aR[k]);
                aI[k] = fmaf(cI, tv, aI[k]);
            }
            if (nk == 7) {
                float cR = c1g[600 + 2 * i];
                float cI = c1g[600 + 2 * i + 1];
                aR[6] = fmaf(cR, tv, aR[6]);
                aI[6] = fmaf(cI, tv, aI[6]);
            }
        }
        const float* wn = ws + WS_WN;
        for (int k = 0; k < nk; ++k) {
            float wv = wn[(M0 + k) * 16 + (lane >> 2)];
            opcs[M0 + k][lane] = make_float2(aR[k] * wv, aI[k] * wv);
        }
    }
    __syncthreads();

    // phase 3: G[m][cc] = sum_j opc[m][j]*e2t[j][cc]; absG (aliases TB) = |G|
    {
        float bR[7], bI[7];
        #pragma unroll
        for (int k = 0; k < 7; ++k) { bR[k] = 0.f; bI[k] = 0.f; }
        const float2* e2t = (const float2*)(ws + WS_E2T);
        const int ccg = (lane < 52) ? lane : 51;
        #pragma unroll 4
        for (int j = 0; j < 64; ++j) {
            float2 ev = e2t[j * 52 + ccg];
            #pragma unroll
            for (int k = 0; k < 6; ++k) {
                float2 ov = opcs[M0 + k][j];   // broadcast; adjacent m fusable
                bR[k] = fmaf(ov.x, ev.x, bR[k]);
                bR[k] = fmaf(-ov.y, ev.y, bR[k]);
                bI[k] = fmaf(ov.x, ev.y, bI[k]);
                bI[k] = fmaf(ov.y, ev.x, bI[k]);
            }
            if (nk == 7) {
                float2 ov = opcs[M0 + 6][j];
                bR[6] = fmaf(ov.x, ev.x, bR[6]);
                bR[6] = fmaf(-ov.y, ev.y, bR[6]);
                bI[6] = fmaf(ov.x, ev.y, bI[6]);
                bI[6] = fmaf(ov.y, ev.x, bI[6]);
            }
        }
        if (lane < 52) {
            for (int k = 0; k < nk; ++k)
                TB[(M0 + k) * 52 + lane] = sqrtf(bR[k] * bR[k] + bI[k] * bI[k]);
        }
    }
    __syncthreads();

    // phase 4: pool absG (2x3/2x1) and pool raw amp; r = v/a (amp-norm cancels)
    const float* aa = ws + WS_AMPA;
    float local = 0.f;
    for (int o = t; o < 1300; o += 512) {
        int hh = o / 50, w = o - hh * 50;
        int h = hh + 12;
        int m1 = 2 * h - 25, m2 = m1 + 1;
        float v = 0.f;
        #pragma unroll
        for (int du = 0; du < 3; ++du) {
            int u = w + du;
            if (m1 >= 0) v = fmaxf(v, TB[m1 * 52 + u]);
            if (m2 < 50) v = fmaxf(v, TB[m2 * 52 + u]);
        }
        float a = 0.f;
        #pragma unroll
        for (int ds = 0; ds < 2; ++ds)
            #pragma unroll
            for (int du = 0; du < 3; ++du)
                a = fmaxf(a, aa[(2 * h + ds) * 52 + w + du]);
        float r = v / a;
        res_s[hh][w] = r;
        local = fmaxf(local, r);
    }
    #pragma unroll
    for (int off = 32; off > 0; off >>= 1)
        local = fmaxf(local, __shfl_xor(local, off));
    if (lane == 0) red8[wid] = local;
    __syncthreads();
    float mres = red8[0];
    #pragma unroll
    for (int i = 1; i < 8; ++i) mres = fmaxf(mres, red8[i]);
    float invm = 1.f / (mres + EPS);

    // phase 5: out[b,r,c] = bias[r,c] + res[c,r]*invm * imax[r]*wmax[c]
    const float* wmaxg = ws + WS_WMAX;
    for (int o = t; o < 2450; o += 512) {
        int r = o / 50, c = o - r * 50;
        float val = bias[o];
        if (c >= 12 && c < 38)
            val = fmaf(res_s[c - 12][r] * invm, imax_s[r] * wmaxg[c], val);
        out[b * 2450 + o] = val;
    }
}

extern "C" void kernel_launch(void* const* d_in, const int* in_sizes, int n_in,
                              void* d_out, int out_size, void* d_ws, size_t ws_size,
                              hipStream_t stream) {
    const float* in   = (const float*)d_in[0];   // [512,1,28,28]
    const float* w    = (const float*)d_in[1];   // [50,16]
    const float* bias = (const float*)d_in[2];   // [1,49,50]
    const float* fs   = (const float*)d_in[3];   // [200,200]
    float* out = (float*)d_out;                  // [512,49,50] f32
    float* ws  = (float*)d_ws;

    hipLaunchKernelGGL(k_prelude, dim3(90),  dim3(256), 0, stream, w, fs, ws);
    hipLaunchKernelGGL(k_main,    dim3(512), dim3(512), 0, stream, in, bias, fs, ws, out);
}

// Round 4
// 43.774 us; speedup vs baseline: 3.3229x; 1.1592x over previous
//
#include <hip/hip_runtime.h>
#include <math.h>

#define EPS 1e-8f
#define TWOPI 6.2831853071795864769f

// ws layout (float offsets)
#define WS_WMAX 0        // 50
#define WS_WN   64       // 50*16
#define WS_C1   1024     // float2 c1[50][50]  (5000 floats)
#define WS_E2T  6144     // float2 e2t[64][52] (6656 floats)
#define WS_RCPA 12800    // float [100][52]    reciprocal of |fft_sig| window

// ---------------- fused prologue: ampabs (blocks 0..81) + tables (82..89) ----
__global__ __launch_bounds__(256) void k_prelude(const float* __restrict__ w,
                                                 const float* __restrict__ fs,
                                                 float* __restrict__ ws) {
    const int blk = blockIdx.x, t = threadIdx.x;
    if (blk < 82) {
        // 1/|fft(full_sig, axis=0)| at shifted rows 50..149, cols 101..152
        __shared__ float tc[200], tsn[200];
        for (int i = t; i < 200; i += 256) {
            float s, c;
            sincosf(-TWOPI * (float)i / 200.f, &s, &c);
            tc[i] = c; tsn[i] = s;
        }
        __syncthreads();
        int gid = blk * 256 + t;
        int q = gid >> 2, part = gid & 3;
        float aR = 0.f, aI = 0.f;
        if (q < 5200) {
            int s_ = q / 52, u = q - s_ * 52;
            int k = (150 + s_) % 200;
            int j = 101 + u;
            int ph = (k * (part * 50)) % 200;
            for (int r = part * 50; r < part * 50 + 50; ++r) {
                float v = fs[r * 200 + j];
                aR = fmaf(v, tc[ph], aR);
                aI = fmaf(v, tsn[ph], aI);
                ph += k; if (ph >= 200) ph -= 200;
            }
        }
        aR += __shfl_xor(aR, 1); aI += __shfl_xor(aI, 1);
        aR += __shfl_xor(aR, 2); aI += __shfl_xor(aI, 2);
        if (q < 5200 && part == 0)
            ws[WS_RCPA + q] = 1.0f / sqrtf(aR * aR + aI * aI);
    } else {
        int gid = (blk - 82) * 256 + t;   // 0..2047
        if (gid < 50) {
            float mx = 0.f, vals[16];
            for (int q = 0; q < 16; ++q) {
                float v = fabsf(w[gid * 16 + q]);
                vals[q] = v; mx = fmaxf(mx, v);
            }
            ws[WS_WMAX + gid] = mx;
            float d = mx + EPS;
            for (int q = 0; q < 16; ++q) ws[WS_WN + gid * 16 + q] = vals[q] / d;
        }
        // c1[m][i]: k(m)=(175+m)%200, phase = -(2pi/200)*((k*(75+i))%200)
        for (int o = gid; o < 2500; o += 2048) {
            int m = o / 50, i = o - m * 50;
            int k = (175 + m) % 200;
            int ph = (k * (75 + i)) % 200;
            float s, c;
            sincosf(-TWOPI * (float)ph / 200.f, &s, &c);
            ws[WS_C1 + 2 * o] = c; ws[WS_C1 + 2 * o + 1] = s;
        }
        // e2t[j][cc] (transposed): phase = -(2pi/200)*(((cc+1)*j)%200)
        for (int o = gid; o < 3328; o += 2048) {
            int j = o / 52, cc = o - j * 52;
            int ph = ((cc + 1) * j) % 200;
            float s, c;
            sincosf(-TWOPI * (float)ph / 200.f, &s, &c);
            ws[WS_E2T + 2 * o] = c; ws[WS_E2T + 2 * o + 1] = s;
        }
    }
}

// ---------------- main batched kernel: one block (512 thr) per batch --------
__global__ __launch_bounds__(512, 4) void k_main(const float* __restrict__ in,
                                                 const float* __restrict__ bias,
                                                 const float* __restrict__ fs,
                                                 const float* __restrict__ ws,
                                                 float* __restrict__ out) {
    __shared__ __align__(16) float2 c1s[50][50];   // 20000 B
    __shared__ __align__(16) float2 e2ts[64][52];  // 26624 B
    __shared__ float TB[3136];                     // 12544 B
    __shared__ float absGs[2600];                  // 10400 B
    __shared__ float xpat[50][16];                 // 3200 B
    __shared__ float imax_s[50];
    __shared__ float inv_s[50];
    __shared__ float res_s[26][50];                // 5200 B
    __shared__ float red8[8];

    const int t = threadIdx.x;
    const int b = blockIdx.x;
    const int lane = t & 63;
    const int wid = t >> 6;
    const int swid = __builtin_amdgcn_readfirstlane(wid);
    const int M0 = swid * 6 + (swid < 2 ? swid : 2);   // contiguous m rows
    const int nk = 6 + (swid < 2 ? 1 : 0);             // waves 0,1 take 7
    const float* ib = in + b * 784;

    // table copies (float4, L2-resident)
    {
        const float4* s1 = (const float4*)(ws + WS_C1);
        float4* d1 = (float4*)&c1s[0][0];
        for (int o = t; o < 1250; o += 512) d1[o] = s1[o];
        const float4* s2 = (const float4*)(ws + WS_E2T);
        float4* d2 = (float4*)&e2ts[0][0];
        for (int o = t; o < 1664; o += 512) d2[o] = s2[o];
    }

    // phase 1: patches (float4) + per-row max via quad shuffle
    if (t < 196) {
        int row = t >> 2, s4 = t & 3;
        int pr = row / 7, pc = row - pr * 7;
        float4 v4 = *(const float4*)(ib + (pr * 4 + s4) * 28 + pc * 4);
        *(float4*)(&xpat[row][s4 * 4]) = v4;
        float mx = fmaxf(fmaxf(v4.x, v4.y), fmaxf(v4.z, v4.w));
        mx = fmaxf(mx, __shfl_xor(mx, 1));
        mx = fmaxf(mx, __shfl_xor(mx, 2));
        if (s4 == 0) { imax_s[row] = mx; inv_s[row] = 1.f / (mx + EPS); }
    }
    __syncthreads();

    // phase 1b: T[i][j] = fs[75+i][j] * xpat[i][j>>2] * inv[i]
    for (int o = t; o < 3136; o += 512) {
        int i = o >> 6, j = o & 63;
        TB[o] = fs[(75 + i) * 200 + j] * xpat[i][j >> 2] * inv_s[i];
    }
    __syncthreads();

    // phase 2: opc[m][j] = (sum_i c1[m][i]*T[i][j]) * wn[m][j>>2]
    // j = lane; the wave's opc stays in registers (aR/aI).
    float aR[7], aI[7];
    #pragma unroll
    for (int k = 0; k < 7; ++k) { aR[k] = 0.f; aI[k] = 0.f; }
    {
        for (int i = 0; i < 48; i += 2) {
            float tv0 = TB[i * 64 + lane];
            float tv1 = TB[i * 64 + 64 + lane];
            #pragma unroll
            for (int k = 0; k < 6; ++k) {
                float4 c4 = *(const float4*)&c1s[M0 + k][i];  // b128 broadcast
                aR[k] = fmaf(c4.x, tv0, aR[k]);
                aI[k] = fmaf(c4.y, tv0, aI[k]);
                aR[k] = fmaf(c4.z, tv1, aR[k]);
                aI[k] = fmaf(c4.w, tv1, aI[k]);
            }
            if (nk == 7) {
                float4 c4 = *(const float4*)&c1s[M0 + 6][i];
                aR[6] = fmaf(c4.x, tv0, aR[6]);
                aI[6] = fmaf(c4.y, tv0, aI[6]);
                aR[6] = fmaf(c4.z, tv1, aR[6]);
                aI[6] = fmaf(c4.w, tv1, aI[6]);
            }
        }
        {   // i = 48 tail
            float tv = TB[48 * 64 + lane];
            #pragma unroll
            for (int k = 0; k < 6; ++k) {
                float2 c = c1s[M0 + k][48];
                aR[k] = fmaf(c.x, tv, aR[k]);
                aI[k] = fmaf(c.y, tv, aI[k]);
            }
            if (nk == 7) {
                float2 c = c1s[M0 + 6][48];
                aR[6] = fmaf(c.x, tv, aR[6]);
                aI[6] = fmaf(c.y, tv, aI[6]);
            }
        }
        const float* wn = ws + WS_WN;
        const int q = lane >> 2;
        #pragma unroll
        for (int k = 0; k < 6; ++k) {
            float wv = wn[(M0 + k) * 16 + q];
            aR[k] *= wv; aI[k] *= wv;
        }
        if (nk == 7) {
            float wv = wn[(M0 + 6) * 16 + q];
            aR[6] *= wv; aI[6] *= wv;
        }
    }
    // NO barrier: phase 3 consumes opc straight from this wave's registers.

    // phase 3: G[m][cc] = sum_j opc[m][j]*e2t[j][cc] via readlane broadcasts
    {
        float bR[7], bI[7];
        #pragma unroll
        for (int k = 0; k < 7; ++k) { bR[k] = 0.f; bI[k] = 0.f; }
        const int ccg = (lane < 52) ? lane : 51;
        #pragma unroll 4
        for (int j = 0; j < 64; ++j) {
            float2 ev = e2ts[j][ccg];
            #pragma unroll
            for (int k = 0; k < 6; ++k) {
                float oR = __int_as_float(__builtin_amdgcn_readlane(__float_as_int(aR[k]), j));
                float oI = __int_as_float(__builtin_amdgcn_readlane(__float_as_int(aI[k]), j));
                bR[k] = fmaf(oR, ev.x, bR[k]);
                bR[k] = fmaf(-oI, ev.y, bR[k]);
                bI[k] = fmaf(oR, ev.y, bI[k]);
                bI[k] = fmaf(oI, ev.x, bI[k]);
            }
            if (nk == 7) {
                float oR = __int_as_float(__builtin_amdgcn_readlane(__float_as_int(aR[6]), j));
                float oI = __int_as_float(__builtin_amdgcn_readlane(__float_as_int(aI[6]), j));
                bR[6] = fmaf(oR, ev.x, bR[6]);
                bR[6] = fmaf(-oI, ev.y, bR[6]);
                bI[6] = fmaf(oR, ev.y, bI[6]);
                bI[6] = fmaf(oI, ev.x, bI[6]);
            }
        }
        if (lane < 52) {
            #pragma unroll
            for (int k = 0; k < 6; ++k)
                absGs[(M0 + k) * 52 + lane] = sqrtf(bR[k] * bR[k] + bI[k] * bI[k]);
            if (nk == 7)
                absGs[(M0 + 6) * 52 + lane] = sqrtf(bR[6] * bR[6] + bI[6] * bI[6]);
        }
    }
    __syncthreads();

    // phase 4: pool absG (2x3/2x1); r = v * min(rcp-amp window)
    const float* ra = ws + WS_RCPA;
    float local = 0.f;
    for (int o = t; o < 1300; o += 512) {
        int hh = o / 50, w = o - hh * 50;
        int h = hh + 12;
        int m1 = 2 * h - 25, m2 = m1 + 1;
        float v = 0.f;
        #pragma unroll
        for (int du = 0; du < 3; ++du) {
            int u = w + du;
            if (m1 >= 0) v = fmaxf(v, absGs[m1 * 52 + u]);
            if (m2 < 50) v = fmaxf(v, absGs[m2 * 52 + u]);
        }
        float rc = ra[(2 * h) * 52 + w];
        #pragma unroll
        for (int du = 1; du < 3; ++du) rc = fminf(rc, ra[(2 * h) * 52 + w + du]);
        #pragma unroll
        for (int du = 0; du < 3; ++du) rc = fminf(rc, ra[(2 * h + 1) * 52 + w + du]);
        float r = v * rc;
        res_s[hh][w] = r;
        local = fmaxf(local, r);
    }
    #pragma unroll
    for (int off = 32; off > 0; off >>= 1)
        local = fmaxf(local, __shfl_xor(local, off));
    if (lane == 0) red8[wid] = local;
    __syncthreads();
    float mres = red8[0];
    #pragma unroll
    for (int i = 1; i < 8; ++i) mres = fmaxf(mres, red8[i]);
    float invm = 1.f / (mres + EPS);

    // phase 5: out[b,r,c] = bias[r,c] + res[c,r]*invm * imax[r]*wmax[c]
    const float* wmaxg = ws + WS_WMAX;
    for (int o = t; o < 2450; o += 512) {
        int r = o / 50, c = o - r * 50;
        float val = bias[o];
        if (c >= 12 && c < 38)
            val = fmaf(res_s[c - 12][r] * invm, imax_s[r] * wmaxg[c], val);
        out[b * 2450 + o] = val;
    }
}

extern "C" void kernel_launch(void* const* d_in, const int* in_sizes, int n_in,
                              void* d_out, int out_size, void* d_ws, size_t ws_size,
                              hipStream_t stream) {
    const float* in   = (const float*)d_in[0];   // [512,1,28,28]
    const float* w    = (const float*)d_in[1];   // [50,16]
    const float* bias = (const float*)d_in[2];   // [1,49,50]
    const float* fs   = (const float*)d_in[3];   // [200,200]
    float* out = (float*)d_out;                  // [512,49,50] f32
    float* ws  = (float*)d_ws;

    hipLaunchKernelGGL(k_prelude, dim3(90),  dim3(256), 0, stream, w, fs, ws);
    hipLaunchKernelGGL(k_main,    dim3(512), dim3(512), 0, stream, in, bias, fs, ws, out);
}

// Round 7
// 43.405 us; speedup vs baseline: 3.3512x; 1.0085x over previous
//
#include <hip/hip_runtime.h>
#include <math.h>

#define EPS 1e-8f
#define TWOPI 6.2831853071795864769f

// ws layout (float offsets)
#define WS_WMAX 0        // 50
#define WS_WN   64       // 50*16
#define WS_C1   1024     // float2 c1[50][50]  (5000 floats)
#define WS_E2T  6144     // float2 e2t[64][52] (6656 floats)
#define WS_RCPA 12800    // float [100][52]    reciprocal of |fft_sig| window

// ---------------- fused prologue: ampabs (blocks 0..81) + tables (82..89) ----
__global__ __launch_bounds__(256) void k_prelude(const float* __restrict__ w,
                                                 const float* __restrict__ fs,
                                                 float* __restrict__ ws) {
    const int blk = blockIdx.x, t = threadIdx.x;
    if (blk < 82) {
        // 1/|fft(full_sig, axis=0)| at shifted rows 50..149, cols 101..152
        __shared__ float tc[200], tsn[200];
        for (int i = t; i < 200; i += 256) {
            float s, c;
            sincosf(-TWOPI * (float)i / 200.f, &s, &c);
            tc[i] = c; tsn[i] = s;
        }
        __syncthreads();
        int gid = blk * 256 + t;
        int q = gid >> 2, part = gid & 3;
        float aR = 0.f, aI = 0.f;
        if (q < 5200) {
            int s_ = q / 52, u = q - s_ * 52;
            int k = (150 + s_) % 200;
            int j = 101 + u;
            int ph = (k * (part * 50)) % 200;
            for (int r = part * 50; r < part * 50 + 50; ++r) {
                float v = fs[r * 200 + j];
                aR = fmaf(v, tc[ph], aR);
                aI = fmaf(v, tsn[ph], aI);
                ph += k; if (ph >= 200) ph -= 200;
            }
        }
        aR += __shfl_xor(aR, 1); aI += __shfl_xor(aI, 1);
        aR += __shfl_xor(aR, 2); aI += __shfl_xor(aI, 2);
        if (q < 5200 && part == 0)
            ws[WS_RCPA + q] = 1.0f / sqrtf(aR * aR + aI * aI);
    } else {
        int gid = (blk - 82) * 256 + t;   // 0..2047
        if (gid < 50) {
            float mx = 0.f, vals[16];
            for (int q = 0; q < 16; ++q) {
                float v = fabsf(w[gid * 16 + q]);
                vals[q] = v; mx = fmaxf(mx, v);
            }
            ws[WS_WMAX + gid] = mx;
            float d = mx + EPS;
            for (int q = 0; q < 16; ++q) ws[WS_WN + gid * 16 + q] = vals[q] / d;
        }
        // c1[m][i]: k(m)=(175+m)%200, phase = -(2pi/200)*((k*(75+i))%200)
        for (int o = gid; o < 2500; o += 2048) {
            int m = o / 50, i = o - m * 50;
            int k = (175 + m) % 200;
            int ph = (k * (75 + i)) % 200;
            float s, c;
            sincosf(-TWOPI * (float)ph / 200.f, &s, &c);
            ws[WS_C1 + 2 * o] = c; ws[WS_C1 + 2 * o + 1] = s;
        }
        // e2t[j][cc] (transposed): phase = -(2pi/200)*(((cc+1)*j)%200)
        for (int o = gid; o < 3328; o += 2048) {
            int j = o / 52, cc = o - j * 52;
            int ph = ((cc + 1) * j) % 200;
            float s, c;
            sincosf(-TWOPI * (float)ph / 200.f, &s, &c);
            ws[WS_E2T + 2 * o] = c; ws[WS_E2T + 2 * o + 1] = s;
        }
    }
}

// ---------------- main batched kernel: one block (1024 thr) per batch --------
__global__ __launch_bounds__(1024, 8) void k_main(const float* __restrict__ in,
                                                  const float* __restrict__ bias,
                                                  const float* __restrict__ fs,
                                                  const float* __restrict__ ws,
                                                  float* __restrict__ out) {
    __shared__ __align__(16) float2 c1s[50][50];   // 20000 B
    __shared__ __align__(16) float2 e2ts[64][52];  // 26624 B
    __shared__ float TB[3136];                     // 12544 B
    __shared__ float absGs[2600];                  // 10400 B
    __shared__ float xpat[50][16];                 // 3200 B
    __shared__ float imax_s[50];
    __shared__ float inv_s[50];
    __shared__ float res_s[26][50];                // 5200 B
    __shared__ float red16[16];

    const int t = threadIdx.x;
    const int b = blockIdx.x;
    const int lane = t & 63;
    const int wid = t >> 6;                               // 0..15
    const int swid = __builtin_amdgcn_readfirstlane(wid);
    // heavy waves (4 m-rows) on wid 0 and 8 -> balanced per SIMD
    const int nk = (swid == 0 || swid == 8) ? 4 : 3;
    const int M0 = 3 * swid + (swid >= 1 ? 1 : 0) + (swid >= 9 ? 1 : 0);
    const float* ib = in + b * 784;

    // table copies (float4, L2-resident)
    {
        const float4* s1 = (const float4*)(ws + WS_C1);
        float4* d1 = (float4*)&c1s[0][0];
        for (int o = t; o < 1250; o += 1024) d1[o] = s1[o];
        const float4* s2 = (const float4*)(ws + WS_E2T);
        float4* d2 = (float4*)&e2ts[0][0];
        for (int o = t; o < 1664; o += 1024) d2[o] = s2[o];
    }

    // phase 1: patches (float4) + per-row max via quad shuffle
    if (t < 196) {
        int row = t >> 2, s4 = t & 3;
        int pr = row / 7, pc = row - pr * 7;
        float4 v4 = *(const float4*)(ib + (pr * 4 + s4) * 28 + pc * 4);
        *(float4*)(&xpat[row][s4 * 4]) = v4;
        float mx = fmaxf(fmaxf(v4.x, v4.y), fmaxf(v4.z, v4.w));
        mx = fmaxf(mx, __shfl_xor(mx, 1));
        mx = fmaxf(mx, __shfl_xor(mx, 2));
        if (s4 == 0) { imax_s[row] = mx; inv_s[row] = 1.f / (mx + EPS); }
    }
    __syncthreads();

    // phase 1b: T[i][j] = fs[75+i][j] * xpat[i][j>>2] * inv[i]
    for (int o = t; o < 3136; o += 1024) {
        int i = o >> 6, j = o & 63;
        TB[o] = fs[(75 + i) * 200 + j] * xpat[i][j >> 2] * inv_s[i];
    }
    __syncthreads();

    // phase 2: opc[m][j] = (sum_i c1[m][i]*T[i][j]) * wn[m][j>>2]
    // j = lane; the wave's opc stays in registers (aR/aI).
    float aR[4], aI[4];
    #pragma unroll
    for (int k = 0; k < 4; ++k) { aR[k] = 0.f; aI[k] = 0.f; }
    {
        for (int i = 0; i < 48; i += 2) {
            float tv0 = TB[i * 64 + lane];
            float tv1 = TB[i * 64 + 64 + lane];
            #pragma unroll
            for (int k = 0; k < 3; ++k) {
                float4 c4 = *(const float4*)&c1s[M0 + k][i];  // b128 broadcast
                aR[k] = fmaf(c4.x, tv0, aR[k]);
                aI[k] = fmaf(c4.y, tv0, aI[k]);
                aR[k] = fmaf(c4.z, tv1, aR[k]);
                aI[k] = fmaf(c4.w, tv1, aI[k]);
            }
            if (nk == 4) {
                float4 c4 = *(const float4*)&c1s[M0 + 3][i];
                aR[3] = fmaf(c4.x, tv0, aR[3]);
                aI[3] = fmaf(c4.y, tv0, aI[3]);
                aR[3] = fmaf(c4.z, tv1, aR[3]);
                aI[3] = fmaf(c4.w, tv1, aI[3]);
            }
        }
        {   // i = 48 tail
            float tv = TB[48 * 64 + lane];
            #pragma unroll
            for (int k = 0; k < 3; ++k) {
                float2 c = c1s[M0 + k][48];
                aR[k] = fmaf(c.x, tv, aR[k]);
                aI[k] = fmaf(c.y, tv, aI[k]);
            }
            if (nk == 4) {
                float2 c = c1s[M0 + 3][48];
                aR[3] = fmaf(c.x, tv, aR[3]);
                aI[3] = fmaf(c.y, tv, aI[3]);
            }
        }
        const float* wn = ws + WS_WN;
        const int q = lane >> 2;
        #pragma unroll
        for (int k = 0; k < 3; ++k) {
            float wv = wn[(M0 + k) * 16 + q];
            aR[k] *= wv; aI[k] *= wv;
        }
        if (nk == 4) {
            float wv = wn[(M0 + 3) * 16 + q];
            aR[3] *= wv; aI[3] *= wv;
        }
    }
    // NO barrier: phase 3 consumes opc straight from this wave's registers.

    // phase 3: G[m][cc] = sum_j opc[m][j]*e2t[j][cc] via readlane broadcasts
    {
        float bR[4], bI[4];
        #pragma unroll
        for (int k = 0; k < 4; ++k) { bR[k] = 0.f; bI[k] = 0.f; }
        const int ccg = (lane < 52) ? lane : 51;
        #pragma unroll 2
        for (int j = 0; j < 64; ++j) {
            float2 ev = e2ts[j][ccg];
            #pragma unroll
            for (int k = 0; k < 3; ++k) {
                float oR = __int_as_float(__builtin_amdgcn_readlane(__float_as_int(aR[k]), j));
                float oI = __int_as_float(__builtin_amdgcn_readlane(__float_as_int(aI[k]), j));
                bR[k] = fmaf(oR, ev.x, bR[k]);
                bR[k] = fmaf(-oI, ev.y, bR[k]);
                bI[k] = fmaf(oR, ev.y, bI[k]);
                bI[k] = fmaf(oI, ev.x, bI[k]);
            }
            if (nk == 4) {
                float oR = __int_as_float(__builtin_amdgcn_readlane(__float_as_int(aR[3]), j));
                float oI = __int_as_float(__builtin_amdgcn_readlane(__float_as_int(aI[3]), j));
                bR[3] = fmaf(oR, ev.x, bR[3]);
                bR[3] = fmaf(-oI, ev.y, bR[3]);
                bI[3] = fmaf(oR, ev.y, bI[3]);
                bI[3] = fmaf(oI, ev.x, bI[3]);
            }
        }
        if (lane < 52) {
            #pragma unroll
            for (int k = 0; k < 3; ++k)
                absGs[(M0 + k) * 52 + lane] = sqrtf(bR[k] * bR[k] + bI[k] * bI[k]);
            if (nk == 4)
                absGs[(M0 + 3) * 52 + lane] = sqrtf(bR[3] * bR[3] + bI[3] * bI[3]);
        }
    }
    __syncthreads();

    // phase 4: pool absG (2x3/2x1); r = v * min(rcp-amp window)
    const float* ra = ws + WS_RCPA;
    float local = 0.f;
    for (int o = t; o < 1300; o += 1024) {
        int hh = o / 50, w = o - hh * 50;
        int h = hh + 12;
        int m1 = 2 * h - 25, m2 = m1 + 1;
        float v = 0.f;
        #pragma unroll
        for (int du = 0; du < 3; ++du) {
            int u = w + du;
            if (m1 >= 0) v = fmaxf(v, absGs[m1 * 52 + u]);
            if (m2 < 50) v = fmaxf(v, absGs[m2 * 52 + u]);
        }
        float rc = ra[(2 * h) * 52 + w];
        #pragma unroll
        for (int du = 1; du < 3; ++du) rc = fminf(rc, ra[(2 * h) * 52 + w + du]);
        #pragma unroll
        for (int du = 0; du < 3; ++du) rc = fminf(rc, ra[(2 * h + 1) * 52 + w + du]);
        float r = v * rc;
        res_s[hh][w] = r;
        local = fmaxf(local, r);
    }
    #pragma unroll
    for (int off = 32; off > 0; off >>= 1)
        local = fmaxf(local, __shfl_xor(local, off));
    if (lane == 0) red16[wid] = local;
    __syncthreads();
    float mres = red16[0];
    #pragma unroll
    for (int i = 1; i < 16; ++i) mres = fmaxf(mres, red16[i]);
    float invm = 1.f / (mres + EPS);

    // phase 5: out[b,r,c] = bias[r,c] + res[c,r]*invm * imax[r]*wmax[c]
    const float* wmaxg = ws + WS_WMAX;
    for (int o = t; o < 2450; o += 1024) {
        int r = o / 50, c = o - r * 50;
        float val = bias[o];
        if (c >= 12 && c < 38)
            val = fmaf(res_s[c - 12][r] * invm, imax_s[r] * wmaxg[c], val);
        out[b * 2450 + o] = val;
    }
}

extern "C" void kernel_launch(void* const* d_in, const int* in_sizes, int n_in,
                              void* d_out, int out_size, void* d_ws, size_t ws_size,
                              hipStream_t stream) {
    const float* in   = (const float*)d_in[0];   // [512,1,28,28]
    const float* w    = (const float*)d_in[1];   // [50,16]
    const float* bias = (const float*)d_in[2];   // [1,49,50]
    const float* fs   = (const float*)d_in[3];   // [200,200]
    float* out = (float*)d_out;                  // [512,49,50] f32
    float* ws  = (float*)d_ws;

    hipLaunchKernelGGL(k_prelude, dim3(90),   dim3(256),  0, stream, w, fs, ws);
    hipLaunchKernelGGL(k_main,    dim3(512),  dim3(1024), 0, stream, in, bias, fs, ws, out);
}

// Round 8
// 43.060 us; speedup vs baseline: 3.3780x; 1.0080x over previous
//
#include <hip/hip_runtime.h>
#include <math.h>

#define EPS 1e-8f
#define TWOPI 6.2831853071795864769f

typedef float f2 __attribute__((ext_vector_type(2)));
static __device__ __forceinline__ f2 f2splat(float v) { f2 r; r[0] = v; r[1] = v; return r; }

// ws layout (float offsets)
#define WS_WMAX 0        // 50
#define WS_WN   64       // 50*16
#define WS_C1   1024     // f2 c1[50][50]  (5000 floats)
#define WS_E2T  6144     // f2 e2t[64][52] (6656 floats)
#define WS_RCPA 12800    // float [100][52]   reciprocal of |fft_sig| window

// ---- fused prologue: ampabs 8-way (blocks 0..162) + tables (163..170) ------
__global__ __launch_bounds__(256) void k_prelude(const float* __restrict__ w,
                                                 const float* __restrict__ fs,
                                                 float* __restrict__ ws) {
    const int blk = blockIdx.x, t = threadIdx.x;
    if (blk < 163) {
        // 1/|fft(full_sig, axis=0)| at shifted rows 50..149, cols 101..152
        __shared__ float tc[200], tsn[200];
        for (int i = t; i < 200; i += 256) {
            float s, c;
            sincosf(-TWOPI * (float)i / 200.f, &s, &c);
            tc[i] = c; tsn[i] = s;
        }
        __syncthreads();
        int gid = blk * 256 + t;
        int q = gid >> 3, part = gid & 7;
        float aR = 0.f, aI = 0.f;
        if (q < 5200) {
            int s_ = q / 52, u = q - s_ * 52;
            int k = (150 + s_) % 200;
            int j = 101 + u;
            int ph = (k * (part * 25)) % 200;
            for (int r = part * 25; r < part * 25 + 25; ++r) {
                float v = fs[r * 200 + j];
                aR = fmaf(v, tc[ph], aR);
                aI = fmaf(v, tsn[ph], aI);
                ph += k; if (ph >= 200) ph -= 200;
            }
        }
        aR += __shfl_xor(aR, 1); aI += __shfl_xor(aI, 1);
        aR += __shfl_xor(aR, 2); aI += __shfl_xor(aI, 2);
        aR += __shfl_xor(aR, 4); aI += __shfl_xor(aI, 4);
        if (q < 5200 && part == 0)
            ws[WS_RCPA + q] = 1.0f / sqrtf(aR * aR + aI * aI);
    } else {
        int gid = (blk - 163) * 256 + t;   // 0..2047
        if (gid < 50) {
            float mx = 0.f, vals[16];
            for (int q = 0; q < 16; ++q) {
                float v = fabsf(w[gid * 16 + q]);
                vals[q] = v; mx = fmaxf(mx, v);
            }
            ws[WS_WMAX + gid] = mx;
            float d = mx + EPS;
            for (int q = 0; q < 16; ++q) ws[WS_WN + gid * 16 + q] = vals[q] / d;
        }
        // c1[m][i]: k(m)=(175+m)%200, phase = -(2pi/200)*((k*(75+i))%200)
        for (int o = gid; o < 2500; o += 2048) {
            int m = o / 50, i = o - m * 50;
            int k = (175 + m) % 200;
            int ph = (k * (75 + i)) % 200;
            float s, c;
            sincosf(-TWOPI * (float)ph / 200.f, &s, &c);
            ws[WS_C1 + 2 * o] = c; ws[WS_C1 + 2 * o + 1] = s;
        }
        // e2t[j][cc] (transposed): phase = -(2pi/200)*(((cc+1)*j)%200)
        for (int o = gid; o < 3328; o += 2048) {
            int j = o / 52, cc = o - j * 52;
            int ph = ((cc + 1) * j) % 200;
            float s, c;
            sincosf(-TWOPI * (float)ph / 200.f, &s, &c);
            ws[WS_E2T + 2 * o] = c; ws[WS_E2T + 2 * o + 1] = s;
        }
    }
}

// ---------------- main batched kernel: one block (1024 thr) per batch --------
__global__ __launch_bounds__(1024, 8) void k_main(const float* __restrict__ in,
                                                  const float* __restrict__ bias,
                                                  const float* __restrict__ fs,
                                                  const float* __restrict__ ws,
                                                  float* __restrict__ out) {
    __shared__ __align__(16) f2 c1s[50][50];       // 20000 B
    __shared__ __align__(16) f2 e2ts[64][52];      // 26624 B
    __shared__ float TB[3136];                     // 12544 B
    __shared__ float absGs[2600];                  // 10400 B
    __shared__ float xpat[50][16];                 // 3200 B
    __shared__ float imax_s[50];
    __shared__ float inv_s[50];
    __shared__ float res_s[26][50];                // 5200 B
    __shared__ __align__(16) float red16[16];

    const int t = threadIdx.x;
    const int b = blockIdx.x;
    const int lane = t & 63;
    const int wid = t >> 6;                               // 0..15
    const int swid = __builtin_amdgcn_readfirstlane(wid);
    // heavy waves (4 m-rows) on wid 0 (SIMD0) and wid 1 (SIMD1) -> max 13 rows/SIMD
    const int nk = (swid < 2) ? 4 : 3;
    const int M0 = (swid < 2) ? 4 * swid : 3 * swid + 2;
    const float* ib = in + b * 784;

    // table copies (float4, L2-resident)
    {
        const float4* s1 = (const float4*)(ws + WS_C1);
        float4* d1 = (float4*)&c1s[0][0];
        for (int o = t; o < 1250; o += 1024) d1[o] = s1[o];
        const float4* s2 = (const float4*)(ws + WS_E2T);
        float4* d2 = (float4*)&e2ts[0][0];
        for (int o = t; o < 1664; o += 1024) d2[o] = s2[o];
    }

    // phase 1: patches (float4) + per-row max via quad shuffle
    if (t < 196) {
        int row = t >> 2, s4 = t & 3;
        int pr = row / 7, pc = row - pr * 7;
        float4 v4 = *(const float4*)(ib + (pr * 4 + s4) * 28 + pc * 4);
        *(float4*)(&xpat[row][s4 * 4]) = v4;
        float mx = fmaxf(fmaxf(v4.x, v4.y), fmaxf(v4.z, v4.w));
        mx = fmaxf(mx, __shfl_xor(mx, 1));
        mx = fmaxf(mx, __shfl_xor(mx, 2));
        if (s4 == 0) { imax_s[row] = mx; inv_s[row] = 1.f / (mx + EPS); }
    }
    __syncthreads();

    // phase 1b: T[i][j] = fs[75+i][j] * xpat[i][j>>2] * inv[i]
    for (int o = t; o < 3136; o += 1024) {
        int i = o >> 6, j = o & 63;
        TB[o] = fs[(75 + i) * 200 + j] * xpat[i][j >> 2] * inv_s[i];
    }
    __syncthreads();

    // phase 2: opc[m][j] = (sum_i c1[m][i]*T[i][j]) * wn[m][j>>2]
    // j = lane; wave's opc stays in registers. Complex MAC as v_pk_fma_f32.
    f2 acc[4];
    #pragma unroll
    for (int k = 0; k < 4; ++k) { acc[k][0] = 0.f; acc[k][1] = 0.f; }
    {
        for (int i = 0; i < 48; i += 2) {
            f2 s0 = f2splat(TB[i * 64 + lane]);
            f2 s1 = f2splat(TB[i * 64 + 64 + lane]);
            #pragma unroll
            for (int k = 0; k < 3; ++k) {
                float4 c4 = *(const float4*)&c1s[M0 + k][i];  // b128 broadcast
                f2 cA; cA[0] = c4.x; cA[1] = c4.y;
                f2 cB; cB[0] = c4.z; cB[1] = c4.w;
                acc[k] = __builtin_elementwise_fma(cA, s0, acc[k]);
                acc[k] = __builtin_elementwise_fma(cB, s1, acc[k]);
            }
            if (nk == 4) {
                float4 c4 = *(const float4*)&c1s[M0 + 3][i];
                f2 cA; cA[0] = c4.x; cA[1] = c4.y;
                f2 cB; cB[0] = c4.z; cB[1] = c4.w;
                acc[3] = __builtin_elementwise_fma(cA, s0, acc[3]);
                acc[3] = __builtin_elementwise_fma(cB, s1, acc[3]);
            }
        }
        {   // i = 48 tail
            f2 sv = f2splat(TB[48 * 64 + lane]);
            #pragma unroll
            for (int k = 0; k < 3; ++k)
                acc[k] = __builtin_elementwise_fma(c1s[M0 + k][48], sv, acc[k]);
            if (nk == 4)
                acc[3] = __builtin_elementwise_fma(c1s[M0 + 3][48], sv, acc[3]);
        }
        const float* wn = ws + WS_WN;
        const int q = lane >> 2;
        #pragma unroll
        for (int k = 0; k < 3; ++k)
            acc[k] *= f2splat(wn[(M0 + k) * 16 + q]);
        if (nk == 4)
            acc[3] *= f2splat(wn[(M0 + 3) * 16 + q]);
    }
    // NO barrier: phase 3 consumes opc straight from this wave's registers.

    // phase 3: G[m][cc] = sum_j opc[m][j]*e2t[j][cc] via readlane broadcasts,
    // complex MAC as 2x v_pk_fma_f32: (bR,bI) += oR*(ex,ey) + oI*(-ey,ex)
    {
        f2 bb[4];
        #pragma unroll
        for (int k = 0; k < 4; ++k) { bb[k][0] = 0.f; bb[k][1] = 0.f; }
        const int ccg = (lane < 52) ? lane : 51;
        #pragma unroll 2
        for (int j = 0; j < 64; ++j) {
            f2 ev = e2ts[j][ccg];
            f2 evr; evr[0] = -ev[1]; evr[1] = ev[0];
            #pragma unroll
            for (int k = 0; k < 3; ++k) {
                float oR = __int_as_float(__builtin_amdgcn_readlane(__float_as_int(acc[k][0]), j));
                float oI = __int_as_float(__builtin_amdgcn_readlane(__float_as_int(acc[k][1]), j));
                bb[k] = __builtin_elementwise_fma(f2splat(oR), ev, bb[k]);
                bb[k] = __builtin_elementwise_fma(f2splat(oI), evr, bb[k]);
            }
            if (nk == 4) {
                float oR = __int_as_float(__builtin_amdgcn_readlane(__float_as_int(acc[3][0]), j));
                float oI = __int_as_float(__builtin_amdgcn_readlane(__float_as_int(acc[3][1]), j));
                bb[3] = __builtin_elementwise_fma(f2splat(oR), ev, bb[3]);
                bb[3] = __builtin_elementwise_fma(f2splat(oI), evr, bb[3]);
            }
        }
        if (lane < 52) {
            #pragma unroll
            for (int k = 0; k < 3; ++k)
                absGs[(M0 + k) * 52 + lane] = sqrtf(bb[k][0] * bb[k][0] + bb[k][1] * bb[k][1]);
            if (nk == 4)
                absGs[(M0 + 3) * 52 + lane] = sqrtf(bb[3][0] * bb[3][0] + bb[3][1] * bb[3][1]);
        }
    }
    __syncthreads();

    // phase 4: pool absG (2x3/2x1); r = v * min(rcp-amp window)
    const float* ra = ws + WS_RCPA;
    float local = 0.f;
    for (int o = t; o < 1300; o += 1024) {
        int hh = o / 50, w = o - hh * 50;
        int h = hh + 12;
        int m1 = 2 * h - 25, m2 = m1 + 1;
        float v = 0.f;
        #pragma unroll
        for (int du = 0; du < 3; ++du) {
            int u = w + du;
            if (m1 >= 0) v = fmaxf(v, absGs[m1 * 52 + u]);
            if (m2 < 50) v = fmaxf(v, absGs[m2 * 52 + u]);
        }
        float rc = ra[(2 * h) * 52 + w];
        #pragma unroll
        for (int du = 1; du < 3; ++du) rc = fminf(rc, ra[(2 * h) * 52 + w + du]);
        #pragma unroll
        for (int du = 0; du < 3; ++du) rc = fminf(rc, ra[(2 * h + 1) * 52 + w + du]);
        float r = v * rc;
        res_s[hh][w] = r;
        local = fmaxf(local, r);
    }
    #pragma unroll
    for (int off = 32; off > 0; off >>= 1)
        local = fmaxf(local, __shfl_xor(local, off));
    if (lane == 0) red16[wid] = local;
    __syncthreads();
    float mres;
    {
        float4 r0 = *(const float4*)&red16[0];
        float4 r1 = *(const float4*)&red16[4];
        float4 r2 = *(const float4*)&red16[8];
        float4 r3 = *(const float4*)&red16[12];
        float m0 = fmaxf(fmaxf(r0.x, r0.y), fmaxf(r0.z, r0.w));
        float m1 = fmaxf(fmaxf(r1.x, r1.y), fmaxf(r1.z, r1.w));
        float m2 = fmaxf(fmaxf(r2.x, r2.y), fmaxf(r2.z, r2.w));
        float m3 = fmaxf(fmaxf(r3.x, r3.y), fmaxf(r3.z, r3.w));
        mres = fmaxf(fmaxf(m0, m1), fmaxf(m2, m3));
    }
    float invm = 1.f / (mres + EPS);

    // phase 5: out[b,r,c] = bias[r,c] + res[c,r]*invm * imax[r]*wmax[c]
    const float* wmaxg = ws + WS_WMAX;
    for (int o = t; o < 2450; o += 1024) {
        int r = o / 50, c = o - r * 50;
        float val = bias[o];
        if (c >= 12 && c < 38)
            val = fmaf(res_s[c - 12][r] * invm, imax_s[r] * wmaxg[c], val);
        out[b * 2450 + o] = val;
    }
}

extern "C" void kernel_launch(void* const* d_in, const int* in_sizes, int n_in,
                              void* d_out, int out_size, void* d_ws, size_t ws_size,
                              hipStream_t stream) {
    const float* in   = (const float*)d_in[0];   // [512,1,28,28]
    const float* w    = (const float*)d_in[1];   // [50,16]
    const float* bias = (const float*)d_in[2];   // [1,49,50]
    const float* fs   = (const float*)d_in[3];   // [200,200]
    float* out = (float*)d_out;                  // [512,49,50] f32
    float* ws  = (float*)d_ws;

    hipLaunchKernelGGL(k_prelude, dim3(171),  dim3(256),  0, stream, w, fs, ws);
    hipLaunchKernelGGL(k_main,    dim3(512),  dim3(1024), 0, stream, in, bias, fs, ws, out);
}

// Round 9
// 35.649 us; speedup vs baseline: 4.0802x; 1.2079x over previous
//
#include <hip/hip_runtime.h>
#include <math.h>

#define EPS 1e-8f
#define TWOPI 6.2831853071795864769f

typedef _Float16 h8 __attribute__((ext_vector_type(8)));
typedef float f32x16 __attribute__((ext_vector_type(16)));

// ws layout (float offsets)
#define WS_WMAX 0        // 50
#define WS_WN   64       // 800
#define WS_RCPA 1024     // 5200: reciprocal of pooled-able |fft_sig| window
#define WS_A2   8192     // f16 frags [4 tm][8 pks][64 l][8 s] = 16384 f16
#define WS_B3   16384    // f16 frags [4 tn][16 pks][64 l][8 s] = 32768 f16

// Shared A/B fragment k-map (MUST be identical for builders & consumers):
//   row/col = 32*tile + (l&31);  k = 16*ks + 8*(l>>5) + s

// ---- prologue: amp (blocks 0..162) + tables/fragments (163..178) -----------
__global__ __launch_bounds__(256) void k_prelude(const float* __restrict__ w,
                                                 const float* __restrict__ fs,
                                                 float* __restrict__ ws) {
    const int blk = blockIdx.x, t = threadIdx.x;
    if (blk < 163) {
        __shared__ float tc[200], tsn[200];
        for (int i = t; i < 200; i += 256) {
            float s, c;
            sincosf(-TWOPI * (float)i / 200.f, &s, &c);
            tc[i] = c; tsn[i] = s;
        }
        __syncthreads();
        int gid = blk * 256 + t;
        int q = gid >> 3, part = gid & 7;
        float aR = 0.f, aI = 0.f;
        if (q < 5200) {
            int s_ = q / 52, u = q - s_ * 52;
            int k = (150 + s_) % 200;
            int j = 101 + u;
            int ph = (k * (part * 25)) % 200;
            for (int r = part * 25; r < part * 25 + 25; ++r) {
                float v = fs[r * 200 + j];
                aR = fmaf(v, tc[ph], aR);
                aI = fmaf(v, tsn[ph], aI);
                ph += k; if (ph >= 200) ph -= 200;
            }
        }
        aR += __shfl_xor(aR, 1); aI += __shfl_xor(aI, 1);
        aR += __shfl_xor(aR, 2); aI += __shfl_xor(aI, 2);
        aR += __shfl_xor(aR, 4); aI += __shfl_xor(aI, 4);
        if (q < 5200 && part == 0)
            ws[WS_RCPA + q] = 1.0f / sqrtf(aR * aR + aI * aI);
    } else {
        int gid = (blk - 163) * 256 + t;   // 0..4095
        if (gid < 50) {
            float mx = 0.f, vals[16];
            for (int q = 0; q < 16; ++q) {
                float v = fabsf(w[gid * 16 + q]);
                vals[q] = v; mx = fmaxf(mx, v);
            }
            ws[WS_WMAX + gid] = mx;
            float d = mx + EPS;
            for (int q = 0; q < 16; ++q) ws[WS_WN + gid * 16 + q] = vals[q] / d;
        }
        // A2 = [cR(50); cI(50); 0] rows x k(0..48), hi (pks<4) / lo (pks>=4)
        _Float16* A2h = (_Float16*)(ws + WS_A2);
        for (int a = gid; a < 16384; a += 4096) {
            int s = a & 7, l = (a >> 3) & 63, pks = (a >> 9) & 7, tm = a >> 12;
            int part = pks >> 2;
            int row = 32 * tm + (l & 31);
            int k = 16 * (pks & 3) + 8 * (l >> 5) + s;
            float X = 0.f;
            if (row < 100 && k < 49) {
                int m = (row < 50) ? row : row - 50;
                int kk = (175 + m) % 200;
                int ph = (kk * (75 + k)) % 200;
                float sn, cs;
                sincosf(-TWOPI * (float)ph / 200.f, &sn, &cs);
                X = (row < 50) ? cs : sn;
            }
            _Float16 hi = (_Float16)X;
            A2h[a] = part ? (_Float16)(X - (float)hi) : hi;
        }
        // B3 = Bcat[kap 0..127][n 0..103]: n<52: kap<64? eR : -eI ; n>=52: kap<64? eI : eR
        _Float16* B3h = (_Float16*)(ws + WS_B3);
        for (int bI = gid; bI < 32768; bI += 4096) {
            int s = bI & 7, l = (bI >> 3) & 63, pks = (bI >> 9) & 15, tn = bI >> 13;
            int part = pks >> 3;
            int n = 32 * tn + (l & 31);
            int kap = 16 * (pks & 7) + 8 * (l >> 5) + s;
            float X = 0.f;
            if (n < 104) {
                int j = kap & 63, half = kap >> 6;
                int cc = (n < 52) ? n : n - 52;
                int ph = ((cc + 1) * j) % 200;
                float sn, cs;
                sincosf(-TWOPI * (float)ph / 200.f, &sn, &cs);
                X = (n < 52) ? (half ? -sn : cs) : (half ? cs : sn);
            }
            _Float16 hi = (_Float16)X;
            B3h[bI] = part ? (_Float16)(X - (float)hi) : hi;
        }
    }
}

// ---------------- main batched kernel: one block (1024 thr) per batch --------
__global__ __launch_bounds__(1024, 8) void k_main(const float* __restrict__ in,
                                                  const float* __restrict__ bias,
                                                  const float* __restrict__ fs,
                                                  const float* __restrict__ ws,
                                                  float* __restrict__ out) {
    // R1: TB f32[64][64] (16KB) + B2 frags (16KB); later Ocat f32[100][68]; later absGs[2600]
    // R2: A3 frags f16 [2][16][64][8] (32KB); later Gcat f32[50][108]
    __shared__ __align__(16) char R1[32768];
    __shared__ __align__(16) char R2[32768];
    __shared__ float xpat[50][16];
    __shared__ float imax_s[50];
    __shared__ float inv_s[50];
    __shared__ float res_s[26][50];
    __shared__ __align__(16) float red16[16];

    const int t = threadIdx.x;
    const int b = blockIdx.x;
    const int lane = t & 63;
    const int wid = t >> 6;
    const int swid = __builtin_amdgcn_readfirstlane(wid);
    const float* ib = in + b * 784;

    // P0: patches (float4) + per-row max via quad shuffle
    if (t < 196) {
        int row = t >> 2, s4 = t & 3;
        int pr = row / 7, pc = row - pr * 7;
        float4 v4 = *(const float4*)(ib + (pr * 4 + s4) * 28 + pc * 4);
        *(float4*)(&xpat[row][s4 * 4]) = v4;
        float mx = fmaxf(fmaxf(v4.x, v4.y), fmaxf(v4.z, v4.w));
        mx = fmaxf(mx, __shfl_xor(mx, 1));
        mx = fmaxf(mx, __shfl_xor(mx, 2));
        if (s4 == 0) { imax_s[row] = mx; inv_s[row] = 1.f / (mx + EPS); }
    }
    __syncthreads();

    // P1: TB[64][64] f32 (rows >=49 zero)
    float* TB = (float*)R1;
    for (int o = t; o < 4096; o += 1024) {
        int i = o >> 6, j = o & 63;
        TB[o] = (i < 49) ? fs[(75 + i) * 200 + j] * xpat[i][j >> 2] * inv_s[i] : 0.f;
    }
    __syncthreads();

    // P2: B2 frags (T side): group = t = ((tn*8+pks)*64+l); pks<4 hi, >=4 lo
    {
        const int l = t & 63;
        const int pks = (t >> 6) & 7;
        const int part = pks >> 2;
        const int tn = t >> 9;
        const int j = (l & 31) + 32 * tn;
        const int i0 = 16 * (pks & 3) + 8 * (l >> 5);
        h8 outv;
        #pragma unroll
        for (int s = 0; s < 8; ++s) {
            float v = TB[(i0 + s) * 64 + j];
            _Float16 hi = (_Float16)v;
            outv[s] = part ? (_Float16)(v - (float)hi) : hi;
        }
        *(h8*)(R1 + 16384 + (t << 4)) = outv;
    }
    __syncthreads();

    // P3a: ph2 MFMA: D[128][64] = A2([chi|chi|clo]) @ B2([Thi;Tlo;Thi]), 12 K-steps
    f32x16 acc;
    #pragma unroll
    for (int i = 0; i < 16; ++i) acc[i] = 0.f;
    if (wid < 8) {
        const int tm = swid >> 1, tn = swid & 1;
        const h8* wsA2 = (const h8*)ws + 2048;   // byte 32768
        #pragma unroll
        for (int ks = 0; ks < 12; ++ks) {
            int pA = (ks < 4) ? ks : ks - 4;     // chi phys 0..3, clo 4..7
            int pB = (ks < 8) ? ks : ks - 8;     // Thi 0..3, Tlo 4..7
            h8 a = wsA2[(tm * 8 + pA) * 64 + lane];
            h8 bf = *(const h8*)(R1 + 16384 + (((tn * 8 + pB) * 64 + lane) << 4));
            acc = __builtin_amdgcn_mfma_f32_32x32x16_f16(a, bf, acc, 0, 0, 0);
        }
    }
    __syncthreads();
    // P3b: D2 -> Ocat f32 [100][68] (overlays R1), scaled by wn
    if (wid < 8) {
        const int tm = swid >> 1, tn = swid & 1;
        const int colj = (lane & 31) + 32 * tn;
        float* Oc = (float*)R1;
        const float* wn = ws + WS_WN;
        #pragma unroll
        for (int r = 0; r < 16; ++r) {
            int row = (r & 3) + 8 * (r >> 2) + 4 * (lane >> 5) + 32 * tm;
            if (row < 100) {
                int m = (row < 50) ? row : row - 50;
                Oc[row * 68 + colj] = acc[r] * wn[m * 16 + (colj >> 2)];
            }
        }
    }
    __syncthreads();

    // P4: A3 frags (opc side) from Ocat; phys 0..7 hi, 8..15 lo
    {
        const float* Oc = (const float*)R1;
        const int l = t & 63;
        const int pks = (t >> 6) & 15;
        const int part = pks >> 3;
        const int kap0 = 16 * (pks & 7) + 8 * (l >> 5);
        #pragma unroll
        for (int tm3 = 0; tm3 < 2; ++tm3) {
            const int m = (l & 31) + 32 * tm3;
            h8 outv;
            if (m < 50) {
                int srow = (kap0 < 64) ? m : m + 50;
                int scol = kap0 & 63;
                float4 v0 = *(const float4*)(Oc + srow * 68 + scol);
                float4 v1 = *(const float4*)(Oc + srow * 68 + scol + 4);
                float vv[8] = {v0.x, v0.y, v0.z, v0.w, v1.x, v1.y, v1.z, v1.w};
                #pragma unroll
                for (int s = 0; s < 8; ++s) {
                    _Float16 hi = (_Float16)vv[s];
                    outv[s] = part ? (_Float16)(vv[s] - (float)hi) : hi;
                }
            } else {
                #pragma unroll
                for (int s = 0; s < 8; ++s) outv[s] = (_Float16)0.f;
            }
            *(h8*)(R2 + (((tm3 * 16 + pks) * 64 + l) << 4)) = outv;
        }
    }
    __syncthreads();

    // P5a: ph3 MFMA: G[64][128] = A3([Ohi|Ohi|Olo]) @ B3([Bhi;Blo;Bhi]), 24 K-steps
    #pragma unroll
    for (int i = 0; i < 16; ++i) acc[i] = 0.f;
    if (wid < 8) {
        const int tm3 = swid >> 2, tn3 = swid & 3;
        const h8* wsB3 = (const h8*)ws + 4096;   // byte 65536
        #pragma unroll
        for (int ks = 0; ks < 24; ++ks) {
            int pA = (ks < 8) ? ks : ks - 8;       // hi 0..7, lo 8..15
            int pB = (ks < 16) ? ks : ks - 16;     // Bhi 0..7, Blo 8..15
            h8 a = *(const h8*)(R2 + (((tm3 * 16 + pA) * 64 + lane) << 4));
            h8 bf = wsB3[(tn3 * 16 + pB) * 64 + lane];
            acc = __builtin_amdgcn_mfma_f32_32x32x16_f16(a, bf, acc, 0, 0, 0);
        }
    }
    __syncthreads();
    // P5b: D3 -> Gcat f32 [50][108] (overlays R2)
    if (wid < 8) {
        const int tm3 = swid >> 2, tn3 = swid & 3;
        const int n = (lane & 31) + 32 * tn3;
        float* Gc = (float*)R2;
        if (n < 104) {
            #pragma unroll
            for (int r = 0; r < 16; ++r) {
                int row = (r & 3) + 8 * (r >> 2) + 4 * (lane >> 5) + 32 * tm3;
                if (row < 50) Gc[row * 108 + n] = acc[r];
            }
        }
    }
    __syncthreads();

    // P6: absG[m*52+cc] = |GR + i GI|  (overlays R1)
    {
        const float* Gc = (const float*)R2;
        float* aG = (float*)R1;
        for (int o = t; o < 2600; o += 1024) {
            int m = o / 52, cc = o - m * 52;
            float gr = Gc[m * 108 + cc], gi = Gc[m * 108 + 52 + cc];
            aG[o] = sqrtf(gr * gr + gi * gi);
        }
    }
    __syncthreads();

    // P7: pool absG (2x3/2x1); r = v * min(rcp-amp window)
    const float* ra = ws + WS_RCPA;
    const float* aG = (const float*)R1;
    float local = 0.f;
    for (int o = t; o < 1300; o += 1024) {
        int hh = o / 50, w2 = o - hh * 50;
        int h = hh + 12;
        int m1 = 2 * h - 25, m2 = m1 + 1;
        float v = 0.f;
        #pragma unroll
        for (int du = 0; du < 3; ++du) {
            int u = w2 + du;
            if (m1 >= 0) v = fmaxf(v, aG[m1 * 52 + u]);
            if (m2 < 50) v = fmaxf(v, aG[m2 * 52 + u]);
        }
        float rc = ra[(2 * h) * 52 + w2];
        #pragma unroll
        for (int du = 1; du < 3; ++du) rc = fminf(rc, ra[(2 * h) * 52 + w2 + du]);
        #pragma unroll
        for (int du = 0; du < 3; ++du) rc = fminf(rc, ra[(2 * h + 1) * 52 + w2 + du]);
        float r = v * rc;
        res_s[hh][w2] = r;
        local = fmaxf(local, r);
    }
    #pragma unroll
    for (int off = 32; off > 0; off >>= 1)
        local = fmaxf(local, __shfl_xor(local, off));
    if (lane == 0) red16[wid] = local;
    __syncthreads();
    float mres;
    {
        float4 r0 = *(const float4*)&red16[0];
        float4 r1 = *(const float4*)&red16[4];
        float4 r2 = *(const float4*)&red16[8];
        float4 r3 = *(const float4*)&red16[12];
        float m0 = fmaxf(fmaxf(r0.x, r0.y), fmaxf(r0.z, r0.w));
        float m1 = fmaxf(fmaxf(r1.x, r1.y), fmaxf(r1.z, r1.w));
        float m2 = fmaxf(fmaxf(r2.x, r2.y), fmaxf(r2.z, r2.w));
        float m3 = fmaxf(fmaxf(r3.x, r3.y), fmaxf(r3.z, r3.w));
        mres = fmaxf(fmaxf(m0, m1), fmaxf(m2, m3));
    }
    float invm = 1.f / (mres + EPS);

    // P9: out[b,r,c] = bias[r,c] + res[c,r]*invm * imax[r]*wmax[c]
    const float* wmaxg = ws + WS_WMAX;
    for (int o = t; o < 2450; o += 1024) {
        int r = o / 50, c = o - r * 50;
        float val = bias[o];
        if (c >= 12 && c < 38)
            val = fmaf(res_s[c - 12][r] * invm, imax_s[r] * wmaxg[c], val);
        out[b * 2450 + o] = val;
    }
}

extern "C" void kernel_launch(void* const* d_in, const int* in_sizes, int n_in,
                              void* d_out, int out_size, void* d_ws, size_t ws_size,
                              hipStream_t stream) {
    const float* in   = (const float*)d_in[0];   // [512,1,28,28]
    const float* w    = (const float*)d_in[1];   // [50,16]
    const float* bias = (const float*)d_in[2];   // [1,49,50]
    const float* fs   = (const float*)d_in[3];   // [200,200]
    float* out = (float*)d_out;                  // [512,49,50] f32
    float* ws  = (float*)d_ws;

    hipLaunchKernelGGL(k_prelude, dim3(179),  dim3(256),  0, stream, w, fs, ws);
    hipLaunchKernelGGL(k_main,    dim3(512),  dim3(1024), 0, stream, in, bias, fs, ws, out);
}

// Round 10
// 34.341 us; speedup vs baseline: 4.2357x; 1.0381x over previous
//
#include <hip/hip_runtime.h>
#include <math.h>

#define EPS 1e-8f
#define TWOPI 6.2831853071795864769f

typedef _Float16 h8 __attribute__((ext_vector_type(8)));
typedef float f32x16 __attribute__((ext_vector_type(16)));

// ws layout (float offsets)
#define WS_WMAX 0        // 50
#define WS_WN   64       // 800
#define WS_RCPA 1024     // 5200: reciprocal of |fft_sig| window
#define WS_A2   8192     // f16 frags [4 tm][8 pks][64 l][8 s] = 16384 f16
#define WS_B3   16384    // f16 frags [4 tn][16 pks][64 l][8 s] = 32768 f16 (INTERLEAVED cols)

// Shared A/B fragment k-map (identical for builders & consumers):
//   row/col = 32*tile + (l&31);  k = 16*ks + 8*(l>>5) + s

// ---- prologue: amp (blocks 0..162) + tables/fragments (163..178) -----------
__global__ __launch_bounds__(256) void k_prelude(const float* __restrict__ w,
                                                 const float* __restrict__ fs,
                                                 float* __restrict__ ws) {
    const int blk = blockIdx.x, t = threadIdx.x;
    if (blk < 163) {
        __shared__ float tc[200], tsn[200];
        for (int i = t; i < 200; i += 256) {
            float s, c;
            sincosf(-TWOPI * (float)i / 200.f, &s, &c);
            tc[i] = c; tsn[i] = s;
        }
        __syncthreads();
        int gid = blk * 256 + t;
        int q = gid >> 3, part = gid & 7;
        float aR = 0.f, aI = 0.f;
        if (q < 5200) {
            int s_ = q / 52, u = q - s_ * 52;
            int k = (150 + s_) % 200;
            int j = 101 + u;
            int ph = (k * (part * 25)) % 200;
            for (int r = part * 25; r < part * 25 + 25; ++r) {
                float v = fs[r * 200 + j];
                aR = fmaf(v, tc[ph], aR);
                aI = fmaf(v, tsn[ph], aI);
                ph += k; if (ph >= 200) ph -= 200;
            }
        }
        aR += __shfl_xor(aR, 1); aI += __shfl_xor(aI, 1);
        aR += __shfl_xor(aR, 2); aI += __shfl_xor(aI, 2);
        aR += __shfl_xor(aR, 4); aI += __shfl_xor(aI, 4);
        if (q < 5200 && part == 0)
            ws[WS_RCPA + q] = 1.0f / sqrtf(aR * aR + aI * aI);
    } else {
        int gid = (blk - 163) * 256 + t;   // 0..4095
        if (gid < 50) {
            float mx = 0.f, vals[16];
            for (int q = 0; q < 16; ++q) {
                float v = fabsf(w[gid * 16 + q]);
                vals[q] = v; mx = fmaxf(mx, v);
            }
            ws[WS_WMAX + gid] = mx;
            float d = mx + EPS;
            for (int q = 0; q < 16; ++q) ws[WS_WN + gid * 16 + q] = vals[q] / d;
        }
        // A2 = [cR(50); cI(50); 0] rows x k(0..48), hi (pks<4) / lo (pks>=4)
        _Float16* A2h = (_Float16*)(ws + WS_A2);
        for (int a = gid; a < 16384; a += 4096) {
            int s = a & 7, l = (a >> 3) & 63, pks = (a >> 9) & 7, tm = a >> 12;
            int part = pks >> 2;
            int row = 32 * tm + (l & 31);
            int k = 16 * (pks & 3) + 8 * (l >> 5) + s;
            float X = 0.f;
            if (row < 100 && k < 49) {
                int m = (row < 50) ? row : row - 50;
                int kk = (175 + m) % 200;
                int ph = (kk * (75 + k)) % 200;
                float sn, cs;
                sincosf(-TWOPI * (float)ph / 200.f, &sn, &cs);
                X = (row < 50) ? cs : sn;
            }
            _Float16 hi = (_Float16)X;
            A2h[a] = part ? (_Float16)(X - (float)hi) : hi;
        }
        // B3 INTERLEAVED: col n' = 2*cc + isI (0..103)
        //   isI=0: kap<64 ? eR : -eI ;  isI=1: kap<64 ? eI : eR
        _Float16* B3h = (_Float16*)(ws + WS_B3);
        for (int bI = gid; bI < 32768; bI += 4096) {
            int s = bI & 7, l = (bI >> 3) & 63, pks = (bI >> 9) & 15, tn = bI >> 13;
            int part = pks >> 3;
            int np = 32 * tn + (l & 31);
            int kap = 16 * (pks & 7) + 8 * (l >> 5) + s;
            float X = 0.f;
            if (np < 104) {
                int cc = np >> 1;
                int j = kap & 63;
                int ph = ((cc + 1) * j) % 200;
                float sn, cs;
                sincosf(-TWOPI * (float)ph / 200.f, &sn, &cs);
                X = (np & 1) ? ((kap < 64) ? sn : cs) : ((kap < 64) ? cs : -sn);
            }
            _Float16 hi = (_Float16)X;
            B3h[bI] = part ? (_Float16)(X - (float)hi) : hi;
        }
    }
}

// ---------------- main batched kernel: one block (1024 thr) per batch --------
__global__ __launch_bounds__(1024, 8) void k_main(const float* __restrict__ in,
                                                  const float* __restrict__ bias,
                                                  const float* __restrict__ fs,
                                                  const float* __restrict__ ws,
                                                  float* __restrict__ out) {
    __shared__ __align__(16) char R1[16384];   // B2 frags; later absG f32[2600]
    __shared__ __align__(16) char R2[32768];   // A3 frags [2 tm3][16 pks][64 l][8 s] f16
    __shared__ float xpat[50][16];
    __shared__ float imax_s[50];
    __shared__ float inv_s[50];
    __shared__ float res_s[26][50];
    __shared__ __align__(16) float red16[16];

    const int t = threadIdx.x;
    const int b = blockIdx.x;
    const int lane = t & 63;
    const int wid = t >> 6;
    const int swid = __builtin_amdgcn_readfirstlane(wid);
    const float* ib = in + b * 784;

    // P0: patches (float4) + per-row max via quad shuffle
    if (t < 196) {
        int row = t >> 2, s4 = t & 3;
        int pr = row / 7, pc = row - pr * 7;
        float4 v4 = *(const float4*)(ib + (pr * 4 + s4) * 28 + pc * 4);
        *(float4*)(&xpat[row][s4 * 4]) = v4;
        float mx = fmaxf(fmaxf(v4.x, v4.y), fmaxf(v4.z, v4.w));
        mx = fmaxf(mx, __shfl_xor(mx, 1));
        mx = fmaxf(mx, __shfl_xor(mx, 2));
        if (s4 == 0) { imax_s[row] = mx; inv_s[row] = 1.f / (mx + EPS); }
    }
    __syncthreads();

    // P1: B2 frags DIRECT from fs: T[i][j] = fs[75+i][j]*xpat[i][j>>2]*inv[i]
    // layout [2 tn][8 pks][64 l][8 s], pks 0..3 hi, 4..7 lo
    {
        const int p = t & 511;
        const int shalf = t >> 9;            // 0/1 -> s 0..3 / 4..7
        const int l = p & 63;
        const int ksq = (p >> 6) & 3;
        const int tn = p >> 8;
        const int j = (l & 31) + 32 * tn;
        const int i0 = 16 * ksq + 8 * (l >> 5);
        _Float16* B2h = (_Float16*)R1;
        const int base0 = ((tn * 8 + ksq) * 64 + l) * 8;
        #pragma unroll
        for (int sx = 0; sx < 4; ++sx) {
            int s = shalf * 4 + sx;
            int i = i0 + s;
            float v = 0.f;
            if (i < 49) v = fs[(75 + i) * 200 + j] * xpat[i][j >> 2] * inv_s[i];
            _Float16 hi = (_Float16)v;
            B2h[base0 + s] = hi;
            B2h[base0 + 2048 + s] = (_Float16)(v - (float)hi);
        }
    }
    __syncthreads();

    // P2: ph2 MFMA D[128][64] = A2 @ B2 (12 K-steps), epilogue scatters
    // D*wn directly into A3 frag layout (hi/lo f16)
    if (wid < 8) {
        const int tm = swid >> 1, tn = swid & 1;
        f32x16 acc;
        #pragma unroll
        for (int i = 0; i < 16; ++i) acc[i] = 0.f;
        const h8* wsA2 = (const h8*)(ws + WS_A2);
        #pragma unroll
        for (int ks = 0; ks < 12; ++ks) {
            int pA = (ks < 4) ? ks : ks - 4;     // chi 0..3, clo 4..7
            int pB = (ks < 8) ? ks : ks - 8;     // Thi 0..3, Tlo 4..7
            h8 a = wsA2[(tm * 8 + pA) * 64 + lane];
            h8 bf = *(const h8*)(R1 + (((tn * 8 + pB) * 64 + lane) << 4));
            acc = __builtin_amdgcn_mfma_f32_32x32x16_f16(a, bf, acc, 0, 0, 0);
        }
        const float* wn = ws + WS_WN;
        const int j = (lane & 31) + 32 * tn;
        const int q = j >> 2;
        _Float16* A3h = (_Float16*)R2;
        #pragma unroll
        for (int r = 0; r < 16; ++r) {
            int row = (r & 3) + 8 * (r >> 2) + 4 * (lane >> 5) + 32 * tm;
            if (row < 100) {
                int m = (row < 50) ? row : row - 50;
                float v = acc[r] * wn[m * 16 + q];
                _Float16 hi = (_Float16)v;
                int kap = j + ((row < 50) ? 0 : 64);
                int tm3 = m >> 5;
                int pks = kap >> 4;                           // 0..7
                int lslot = (m & 31) + 32 * ((kap >> 3) & 1);
                int base = ((tm3 * 16 + pks) * 64 + lslot) * 8 + (kap & 7);
                A3h[base] = hi;
                A3h[base + 4096] = (_Float16)(v - (float)hi); // pks+8 block
            }
        }
    }
    __syncthreads();

    // P3: ph3 MFMA G'[64][128] = A3 @ B3' (24 K-steps), epilogue fuses
    // |G| via adjacent-lane shfl (interleaved cols) -> absG (overlays R1)
    if (wid < 8) {
        const int tm3 = swid >> 2, tn3 = swid & 3;
        f32x16 acc;
        #pragma unroll
        for (int i = 0; i < 16; ++i) acc[i] = 0.f;
        const h8* wsB3 = (const h8*)(ws + WS_B3);
        #pragma unroll
        for (int ks = 0; ks < 24; ++ks) {
            int pA = (ks < 8) ? ks : ks - 8;       // Ohi 0..7 (x2), Olo 8..15
            int pB = (ks < 16) ? ks : ks - 16;     // Bhi 0..7, Blo 8..15, Bhi
            h8 a = *(const h8*)(R2 + (((tm3 * 16 + pA) * 64 + lane) << 4));
            h8 bf = wsB3[(tn3 * 16 + pB) * 64 + lane];
            acc = __builtin_amdgcn_mfma_f32_32x32x16_f16(a, bf, acc, 0, 0, 0);
        }
        const int np = (lane & 31) + 32 * tn3;
        float* aG = (float*)R1;
        if (np < 104) {
            const int cc = np >> 1;
            const bool wr = !(np & 1);
            #pragma unroll
            for (int r = 0; r < 16; ++r) {
                int row = (r & 3) + 8 * (r >> 2) + 4 * (lane >> 5) + 32 * tm3;
                float g = acc[r];
                float gp = __shfl_xor(g, 1);
                if (row < 50 && wr) aG[row * 52 + cc] = sqrtf(g * g + gp * gp);
            }
        }
    }
    __syncthreads();

    // P4: pool absG (2x3/2x1); r = v * min(rcp-amp window)
    const float* ra = ws + WS_RCPA;
    const float* aG = (const float*)R1;
    float local = 0.f;
    for (int o = t; o < 1300; o += 1024) {
        int hh = o / 50, w2 = o - hh * 50;
        int h = hh + 12;
        int m1 = 2 * h - 25, m2 = m1 + 1;
        float v = 0.f;
        #pragma unroll
        for (int du = 0; du < 3; ++du) {
            int u = w2 + du;
            if (m1 >= 0) v = fmaxf(v, aG[m1 * 52 + u]);
            if (m2 < 50) v = fmaxf(v, aG[m2 * 52 + u]);
        }
        float rc = ra[(2 * h) * 52 + w2];
        #pragma unroll
        for (int du = 1; du < 3; ++du) rc = fminf(rc, ra[(2 * h) * 52 + w2 + du]);
        #pragma unroll
        for (int du = 0; du < 3; ++du) rc = fminf(rc, ra[(2 * h + 1) * 52 + w2 + du]);
        float r = v * rc;
        res_s[hh][w2] = r;
        local = fmaxf(local, r);
    }
    #pragma unroll
    for (int off = 32; off > 0; off >>= 1)
        local = fmaxf(local, __shfl_xor(local, off));
    if (lane == 0) red16[wid] = local;
    __syncthreads();

    float mres;
    {
        float4 r0 = *(const float4*)&red16[0];
        float4 r1 = *(const float4*)&red16[4];
        float4 r2 = *(const float4*)&red16[8];
        float4 r3 = *(const float4*)&red16[12];
        float m0 = fmaxf(fmaxf(r0.x, r0.y), fmaxf(r0.z, r0.w));
        float m1 = fmaxf(fmaxf(r1.x, r1.y), fmaxf(r1.z, r1.w));
        float m2 = fmaxf(fmaxf(r2.x, r2.y), fmaxf(r2.z, r2.w));
        float m3 = fmaxf(fmaxf(r3.x, r3.y), fmaxf(r3.z, r3.w));
        mres = fmaxf(fmaxf(m0, m1), fmaxf(m2, m3));
    }
    float invm = 1.f / (mres + EPS);

    // P5: out[b,r,c] = bias[r,c] + res[c,r]*invm * imax[r]*wmax[c]
    const float* wmaxg = ws + WS_WMAX;
    for (int o = t; o < 2450; o += 1024) {
        int r = o / 50, c = o - r * 50;
        float val = bias[o];
        if (c >= 12 && c < 38)
            val = fmaf(res_s[c - 12][r] * invm, imax_s[r] * wmaxg[c], val);
        out[b * 2450 + o] = val;
    }
}

extern "C" void kernel_launch(void* const* d_in, const int* in_sizes, int n_in,
                              void* d_out, int out_size, void* d_ws, size_t ws_size,
                              hipStream_t stream) {
    const float* in   = (const float*)d_in[0];   // [512,1,28,28]
    const float* w    = (const float*)d_in[1];   // [50,16]
    const float* bias = (const float*)d_in[2];   // [1,49,50]
    const float* fs   = (const float*)d_in[3];   // [200,200]
    float* out = (float*)d_out;                  // [512,49,50] f32
    float* ws  = (float*)d_ws;

    hipLaunchKernelGGL(k_prelude, dim3(179),  dim3(256),  0, stream, w, fs, ws);
    hipLaunchKernelGGL(k_main,    dim3(512),  dim3(1024), 0, stream, in, bias, fs, ws, out);
}

// Round 11
// 25.986 us; speedup vs baseline: 5.5977x; 1.3215x over previous
//
#include <hip/hip_runtime.h>
#include <math.h>

#define EPS 1e-8f
#define TWOPI 6.2831853071795864769f

typedef _Float16 h8 __attribute__((ext_vector_type(8)));
typedef float f32x16 __attribute__((ext_vector_type(16)));

// ws layout (float offsets)
#define WS_WMAX 0        // 50
#define WS_WN   64       // 800
#define WS_RCPA 1024     // 5200: reciprocal of |fft_sig| window
#define WS_A2   8192     // f16 frags [4 tm][8 pks][64 l][8 s] = 16384 f16
#define WS_B3   16384    // f16 frags [4 tn][16 pks][64 l][8 s] = 32768 f16 (INTERLEAVED cols)

// Shared A/B fragment k-map (identical for builders & consumers):
//   row/col = 32*tile + (l&31);  k = 16*ks + 8*(l>>5) + s

// ---- prologue: amp (blocks 0..162) + tables/fragments (163..178) -----------
__global__ __launch_bounds__(256) void k_prelude(const float* __restrict__ w,
                                                 const float* __restrict__ fs,
                                                 float* __restrict__ ws) {
    const int blk = blockIdx.x, t = threadIdx.x;
    if (blk < 163) {
        __shared__ float tc[200], tsn[200];
        for (int i = t; i < 200; i += 256) {
            float s, c;
            sincosf(-TWOPI * (float)i / 200.f, &s, &c);
            tc[i] = c; tsn[i] = s;
        }
        __syncthreads();
        int gid = blk * 256 + t;
        int q = gid >> 3, part = gid & 7;
        float aR = 0.f, aI = 0.f;
        if (q < 5200) {
            int s_ = q / 52, u = q - s_ * 52;
            int k = (150 + s_) % 200;
            int j = 101 + u;
            int ph = (k * (part * 25)) % 200;
            for (int r = part * 25; r < part * 25 + 25; ++r) {
                float v = fs[r * 200 + j];
                aR = fmaf(v, tc[ph], aR);
                aI = fmaf(v, tsn[ph], aI);
                ph += k; if (ph >= 200) ph -= 200;
            }
        }
        aR += __shfl_xor(aR, 1); aI += __shfl_xor(aI, 1);
        aR += __shfl_xor(aR, 2); aI += __shfl_xor(aI, 2);
        aR += __shfl_xor(aR, 4); aI += __shfl_xor(aI, 4);
        if (q < 5200 && part == 0)
            ws[WS_RCPA + q] = 1.0f / sqrtf(aR * aR + aI * aI);
    } else {
        int gid = (blk - 163) * 256 + t;   // 0..4095
        if (gid < 50) {
            float mx = 0.f, vals[16];
            for (int q = 0; q < 16; ++q) {
                float v = fabsf(w[gid * 16 + q]);
                vals[q] = v; mx = fmaxf(mx, v);
            }
            ws[WS_WMAX + gid] = mx;
            float d = mx + EPS;
            for (int q = 0; q < 16; ++q) ws[WS_WN + gid * 16 + q] = vals[q] / d;
        }
        // A2 = [cR(50); cI(50); 0] rows x k(0..48), hi (pks<4) / lo (pks>=4)
        _Float16* A2h = (_Float16*)(ws + WS_A2);
        for (int a = gid; a < 16384; a += 4096) {
            int s = a & 7, l = (a >> 3) & 63, pks = (a >> 9) & 7, tm = a >> 12;
            int part = pks >> 2;
            int row = 32 * tm + (l & 31);
            int k = 16 * (pks & 3) + 8 * (l >> 5) + s;
            float X = 0.f;
            if (row < 100 && k < 49) {
                int m = (row < 50) ? row : row - 50;
                int kk = (175 + m) % 200;
                int ph = (kk * (75 + k)) % 200;
                float sn, cs;
                sincosf(-TWOPI * (float)ph / 200.f, &sn, &cs);
                X = (row < 50) ? cs : sn;
            }
            _Float16 hi = (_Float16)X;
            A2h[a] = part ? (_Float16)(X - (float)hi) : hi;
        }
        // B3 INTERLEAVED: col n' = 2*cc + isI (0..103)
        //   isI=0: kap<64 ? eR : -eI ;  isI=1: kap<64 ? eI : eR
        _Float16* B3h = (_Float16*)(ws + WS_B3);
        for (int bI = gid; bI < 32768; bI += 4096) {
            int s = bI & 7, l = (bI >> 3) & 63, pks = (bI >> 9) & 15, tn = bI >> 13;
            int part = pks >> 3;
            int np = 32 * tn + (l & 31);
            int kap = 16 * (pks & 7) + 8 * (l >> 5) + s;
            float X = 0.f;
            if (np < 104) {
                int cc = np >> 1;
                int j = kap & 63;
                int ph = ((cc + 1) * j) % 200;
                float sn, cs;
                sincosf(-TWOPI * (float)ph / 200.f, &sn, &cs);
                X = (np & 1) ? ((kap < 64) ? sn : cs) : ((kap < 64) ? cs : -sn);
            }
            _Float16 hi = (_Float16)X;
            B3h[bI] = part ? (_Float16)(X - (float)hi) : hi;
        }
    }
}

// -------- main batched kernel: one block (512 thr = 8 waves) per batch ------
__global__ __launch_bounds__(512, 4) void k_main(const float* __restrict__ in,
                                                 const float* __restrict__ bias,
                                                 const float* __restrict__ fs,
                                                 const float* __restrict__ ws,
                                                 float* __restrict__ out) {
    __shared__ __align__(16) char R1[16384];   // B2 frags; later absG f32[2600]
    __shared__ __align__(16) char R2[32768];   // A3 frags [2 tm3][16 pks][64 l][8 s] f16
    __shared__ float xpat[50][16];
    __shared__ float imax_s[50];
    __shared__ float inv_s[50];
    __shared__ float res_s[26][50];
    __shared__ __align__(16) float red8[8];

    const int t = threadIdx.x;
    const int b = blockIdx.x;
    const int lane = t & 63;
    const int wid = t >> 6;                               // 0..7
    const int swid = __builtin_amdgcn_readfirstlane(wid);
    const float* ib = in + b * 784;

    // P0: patches (float4) + per-row max via quad shuffle
    if (t < 196) {
        int row = t >> 2, s4 = t & 3;
        int pr = row / 7, pc = row - pr * 7;
        float4 v4 = *(const float4*)(ib + (pr * 4 + s4) * 28 + pc * 4);
        *(float4*)(&xpat[row][s4 * 4]) = v4;
        float mx = fmaxf(fmaxf(v4.x, v4.y), fmaxf(v4.z, v4.w));
        mx = fmaxf(mx, __shfl_xor(mx, 1));
        mx = fmaxf(mx, __shfl_xor(mx, 2));
        if (s4 == 0) { imax_s[row] = mx; inv_s[row] = 1.f / (mx + EPS); }
    }
    __syncthreads();

    // P1: B2 frags DIRECT from fs; 512 threads = (tn,ksq,l); 8 s each;
    // two ds_write_b128 per thread (hi block pks=ksq, lo block pks=ksq+4)
    {
        const int l = t & 63;
        const int ksq = (t >> 6) & 3;
        const int tn = t >> 8;               // 0..1
        const int j = (l & 31) + 32 * tn;
        const int i0 = 16 * ksq + 8 * (l >> 5);
        h8 hiv, lov;
        #pragma unroll
        for (int s = 0; s < 8; ++s) {
            int i = i0 + s;
            float v = 0.f;
            if (i < 49) v = fs[(75 + i) * 200 + j] * xpat[i][j >> 2] * inv_s[i];
            _Float16 hi = (_Float16)v;
            hiv[s] = hi;
            lov[s] = (_Float16)(v - (float)hi);
        }
        _Float16* B2h = (_Float16*)R1;
        const int base0 = ((tn * 8 + ksq) * 64 + l) * 8;
        *(h8*)(B2h + base0) = hiv;
        *(h8*)(B2h + base0 + 2048) = lov;
    }
    __syncthreads();

    // P2: ph2 MFMA D[128][64] = A2 @ B2 (12 K-steps), all 8 waves;
    // epilogue scatters D*wn directly into A3 frag layout (hi/lo f16)
    {
        const int tm = swid >> 1, tn = swid & 1;
        f32x16 acc;
        #pragma unroll
        for (int i = 0; i < 16; ++i) acc[i] = 0.f;
        const h8* wsA2 = (const h8*)(ws + WS_A2);
        #pragma unroll
        for (int ks = 0; ks < 12; ++ks) {
            int pA = (ks < 4) ? ks : ks - 4;     // chi 0..3, clo 4..7
            int pB = (ks < 8) ? ks : ks - 8;     // Thi 0..3, Tlo 4..7
            h8 a = wsA2[(tm * 8 + pA) * 64 + lane];
            h8 bf = *(const h8*)(R1 + (((tn * 8 + pB) * 64 + lane) << 4));
            acc = __builtin_amdgcn_mfma_f32_32x32x16_f16(a, bf, acc, 0, 0, 0);
        }
        const float* wn = ws + WS_WN;
        const int j = (lane & 31) + 32 * tn;
        const int q = j >> 2;
        _Float16* A3h = (_Float16*)R2;
        #pragma unroll
        for (int r = 0; r < 16; ++r) {
            int row = (r & 3) + 8 * (r >> 2) + 4 * (lane >> 5) + 32 * tm;
            if (row < 100) {
                int m = (row < 50) ? row : row - 50;
                float v = acc[r] * wn[m * 16 + q];
                _Float16 hi = (_Float16)v;
                int kap = j + ((row < 50) ? 0 : 64);
                int tm3 = m >> 5;
                int pks = kap >> 4;                           // 0..7
                int lslot = (m & 31) + 32 * ((kap >> 3) & 1);
                int base = ((tm3 * 16 + pks) * 64 + lslot) * 8 + (kap & 7);
                A3h[base] = hi;
                A3h[base + 4096] = (_Float16)(v - (float)hi); // pks+8 block
            }
        }
    }
    __syncthreads();

    // P3: ph3 MFMA G'[64][128] = A3 @ B3' (24 K-steps), all 8 waves;
    // epilogue fuses |G| via adjacent-lane shfl -> absG (overlays R1)
    {
        const int tm3 = swid >> 2, tn3 = swid & 3;
        f32x16 acc;
        #pragma unroll
        for (int i = 0; i < 16; ++i) acc[i] = 0.f;
        const h8* wsB3 = (const h8*)(ws + WS_B3);
        #pragma unroll
        for (int ks = 0; ks < 24; ++ks) {
            int pA = (ks < 8) ? ks : ks - 8;       // Ohi 0..7 (x2), Olo 8..15
            int pB = (ks < 16) ? ks : ks - 16;     // Bhi 0..7, Blo 8..15, Bhi
            h8 a = *(const h8*)(R2 + (((tm3 * 16 + pA) * 64 + lane) << 4));
            h8 bf = wsB3[(tn3 * 16 + pB) * 64 + lane];
            acc = __builtin_amdgcn_mfma_f32_32x32x16_f16(a, bf, acc, 0, 0, 0);
        }
        const int np = (lane & 31) + 32 * tn3;
        float* aG = (float*)R1;
        if (np < 104) {
            const int cc = np >> 1;
            const bool wr = !(np & 1);
            #pragma unroll
            for (int r = 0; r < 16; ++r) {
                int row = (r & 3) + 8 * (r >> 2) + 4 * (lane >> 5) + 32 * tm3;
                float g = acc[r];
                float gp = __shfl_xor(g, 1);
                if (row < 50 && wr) aG[row * 52 + cc] = sqrtf(g * g + gp * gp);
            }
        }
    }
    __syncthreads();

    // P4: pool absG (2x3/2x1); r = v * min(rcp-amp window)
    const float* ra = ws + WS_RCPA;
    const float* aG = (const float*)R1;
    float local = 0.f;
    for (int o = t; o < 1300; o += 512) {
        int hh = o / 50, w2 = o - hh * 50;
        int h = hh + 12;
        int m1 = 2 * h - 25, m2 = m1 + 1;
        float v = 0.f;
        #pragma unroll
        for (int du = 0; du < 3; ++du) {
            int u = w2 + du;
            if (m1 >= 0) v = fmaxf(v, aG[m1 * 52 + u]);
            if (m2 < 50) v = fmaxf(v, aG[m2 * 52 + u]);
        }
        float rc = ra[(2 * h) * 52 + w2];
        #pragma unroll
        for (int du = 1; du < 3; ++du) rc = fminf(rc, ra[(2 * h) * 52 + w2 + du]);
        #pragma unroll
        for (int du = 0; du < 3; ++du) rc = fminf(rc, ra[(2 * h + 1) * 52 + w2 + du]);
        float r = v * rc;
        res_s[hh][w2] = r;
        local = fmaxf(local, r);
    }
    #pragma unroll
    for (int off = 32; off > 0; off >>= 1)
        local = fmaxf(local, __shfl_xor(local, off));
    if (lane == 0) red8[wid] = local;
    __syncthreads();

    float mres;
    {
        float4 r0 = *(const float4*)&red8[0];
        float4 r1 = *(const float4*)&red8[4];
        float m0 = fmaxf(fmaxf(r0.x, r0.y), fmaxf(r0.z, r0.w));
        float m1 = fmaxf(fmaxf(r1.x, r1.y), fmaxf(r1.z, r1.w));
        mres = fmaxf(m0, m1);
    }
    float invm = 1.f / (mres + EPS);

    // P5: out[b,r,c] = bias[r,c] + res[c,r]*invm * imax[r]*wmax[c]
    const float* wmaxg = ws + WS_WMAX;
    for (int o = t; o < 2450; o += 512) {
        int r = o / 50, c = o - r * 50;
        float val = bias[o];
        if (c >= 12 && c < 38)
            val = fmaf(res_s[c - 12][r] * invm, imax_s[r] * wmaxg[c], val);
        out[b * 2450 + o] = val;
    }
}

extern "C" void kernel_launch(void* const* d_in, const int* in_sizes, int n_in,
                              void* d_out, int out_size, void* d_ws, size_t ws_size,
                              hipStream_t stream) {
    const float* in   = (const float*)d_in[0];   // [512,1,28,28]
    const float* w    = (const float*)d_in[1];   // [50,16]
    const float* bias = (const float*)d_in[2];   // [1,49,50]
    const float* fs   = (const float*)d_in[3];   // [200,200]
    float* out = (float*)d_out;                  // [512,49,50] f32
    float* ws  = (float*)d_ws;

    hipLaunchKernelGGL(k_prelude, dim3(179),  dim3(256), 0, stream, w, fs, ws);
    hipLaunchKernelGGL(k_main,    dim3(512),  dim3(512), 0, stream, in, bias, fs, ws, out);
}

// Round 12
// 24.812 us; speedup vs baseline: 5.8625x; 1.0473x over previous
//
#include <hip/hip_runtime.h>
#include <math.h>

#define EPS 1e-8f
#define TWOPI 6.2831853071795864769f

typedef _Float16 h8 __attribute__((ext_vector_type(8)));
typedef float f32x16 __attribute__((ext_vector_type(16)));

// ws layout (float offsets)
#define WS_WMAX 0        // 50
#define WS_WN   64       // 800
#define WS_RCPA 1024     // 5200: reciprocal of |fft_sig| window
#define WS_A2   8192     // f16 frags [4 tm][4 pks][64 l][8 s] = 8192 f16 (hi only)
#define WS_B3   16384    // f16 frags [4 tn][16 pks][64 l][8 s] = 32768 f16 (hi+lo, interleaved cols)

// Shared A/B fragment k-map (identical for builders & consumers):
//   row/col = 32*tile + (l&31);  k = 16*ks + 8*(l>>5) + s

// ---- prologue: amp (blocks 0..162) + tables/fragments (163..194) -----------
__global__ __launch_bounds__(256) void k_prelude(const float* __restrict__ w,
                                                 const float* __restrict__ fs,
                                                 float* __restrict__ ws) {
    const int blk = blockIdx.x, t = threadIdx.x;
    if (blk < 163) {
        __shared__ float tc[200], tsn[200];
        for (int i = t; i < 200; i += 256) {
            float s, c;
            sincosf(-TWOPI * (float)i / 200.f, &s, &c);
            tc[i] = c; tsn[i] = s;
        }
        __syncthreads();
        int gid = blk * 256 + t;
        int q = gid >> 3, part = gid & 7;
        float aR = 0.f, aI = 0.f;
        if (q < 5200) {
            int s_ = q / 52, u = q - s_ * 52;
            int k = (150 + s_) % 200;
            int j = 101 + u;
            int ph = (k * (part * 25)) % 200;
            for (int r = part * 25; r < part * 25 + 25; ++r) {
                float v = fs[r * 200 + j];
                aR = fmaf(v, tc[ph], aR);
                aI = fmaf(v, tsn[ph], aI);
                ph += k; if (ph >= 200) ph -= 200;
            }
        }
        aR += __shfl_xor(aR, 1); aI += __shfl_xor(aI, 1);
        aR += __shfl_xor(aR, 2); aI += __shfl_xor(aI, 2);
        aR += __shfl_xor(aR, 4); aI += __shfl_xor(aI, 4);
        if (q < 5200 && part == 0)
            ws[WS_RCPA + q] = 1.0f / sqrtf(aR * aR + aI * aI);
    } else {
        int gid = (blk - 163) * 256 + t;   // 0..8191
        if (gid < 50) {
            float mx = 0.f, vals[16];
            for (int q = 0; q < 16; ++q) {
                float v = fabsf(w[gid * 16 + q]);
                vals[q] = v; mx = fmaxf(mx, v);
            }
            ws[WS_WMAX + gid] = mx;
            float d = mx + EPS;
            for (int q = 0; q < 16; ++q) ws[WS_WN + gid * 16 + q] = vals[q] / d;
        }
        // A2 (hi only) = [cR(50); cI(50); 0] rows x k(0..48)
        {
            _Float16* A2h = (_Float16*)(ws + WS_A2);
            int a = gid;   // exactly 8192 threads
            int s = a & 7, l = (a >> 3) & 63, pks = (a >> 9) & 3, tm = a >> 11;
            int row = 32 * tm + (l & 31);
            int k = 16 * pks + 8 * (l >> 5) + s;
            float X = 0.f;
            if (row < 100 && k < 49) {
                int m = (row < 50) ? row : row - 50;
                int kk = (175 + m) % 200;
                int ph = (kk * (75 + k)) % 200;
                float sn, cs;
                sincosf(-TWOPI * (float)ph / 200.f, &sn, &cs);
                X = (row < 50) ? cs : sn;
            }
            A2h[a] = (_Float16)X;
        }
        // B3 INTERLEAVED: col n' = 2*cc + isI (0..103)
        //   isI=0: kap<64 ? eR : -eI ;  isI=1: kap<64 ? eI : eR
        _Float16* B3h = (_Float16*)(ws + WS_B3);
        for (int bI = gid; bI < 32768; bI += 8192) {
            int s = bI & 7, l = (bI >> 3) & 63, pks = (bI >> 9) & 15, tn = bI >> 13;
            int part = pks >> 3;
            int np = 32 * tn + (l & 31);
            int kap = 16 * (pks & 7) + 8 * (l >> 5) + s;
            float X = 0.f;
            if (np < 104) {
                int cc = np >> 1;
                int j = kap & 63;
                int ph = ((cc + 1) * j) % 200;
                float sn, cs;
                sincosf(-TWOPI * (float)ph / 200.f, &sn, &cs);
                X = (np & 1) ? ((kap < 64) ? sn : cs) : ((kap < 64) ? cs : -sn);
            }
            _Float16 hi = (_Float16)X;
            B3h[bI] = part ? (_Float16)(X - (float)hi) : hi;
        }
    }
}

// -------- main batched kernel: one block (512 thr = 8 waves) per batch ------
__global__ __launch_bounds__(512, 4) void k_main(const float* __restrict__ in,
                                                 const float* __restrict__ bias,
                                                 const float* __restrict__ fs,
                                                 const float* __restrict__ ws,
                                                 float* __restrict__ out) {
    __shared__ __align__(16) char R1[16384];   // B2 frags; later absG f32[2600]
    __shared__ __align__(16) char R2[16640];   // A3 hi frags [2 tm3][8 pks][65 slots][8 s] f16
    __shared__ float xpat[50][16];
    __shared__ float imax_s[50];
    __shared__ float inv_s[50];
    __shared__ float res_s[26][50];
    __shared__ __align__(16) float red8[8];

    const int t = threadIdx.x;
    const int b = blockIdx.x;
    const int lane = t & 63;
    const int wid = t >> 6;                               // 0..7
    const int swid = __builtin_amdgcn_readfirstlane(wid);
    const float* ib = in + b * 784;

    // P0: patches (float4) + per-row max via quad shuffle
    if (t < 196) {
        int row = t >> 2, s4 = t & 3;
        int pr = row / 7, pc = row - pr * 7;
        float4 v4 = *(const float4*)(ib + (pr * 4 + s4) * 28 + pc * 4);
        *(float4*)(&xpat[row][s4 * 4]) = v4;
        float mx = fmaxf(fmaxf(v4.x, v4.y), fmaxf(v4.z, v4.w));
        mx = fmaxf(mx, __shfl_xor(mx, 1));
        mx = fmaxf(mx, __shfl_xor(mx, 2));
        if (s4 == 0) { imax_s[row] = mx; inv_s[row] = 1.f / (mx + EPS); }
    }
    // zero R2 (stale-LDS insurance for unwritten m>=50 slots)
    {
        h8 z;
        #pragma unroll
        for (int s = 0; s < 8; ++s) z[s] = (_Float16)0.f;
        for (int o = t; o < 1040; o += 512) *(h8*)(R2 + (o << 4)) = z;
    }
    __syncthreads();

    // P1: B2 frags DIRECT from fs; 512 threads = (tn,ksq,l); 8 s each;
    // two ds_write_b128 per thread (hi block pks=ksq, lo block pks=ksq+4)
    {
        const int l = t & 63;
        const int ksq = (t >> 6) & 3;
        const int tn = t >> 8;               // 0..1
        const int j = (l & 31) + 32 * tn;
        const int i0 = 16 * ksq + 8 * (l >> 5);
        h8 hiv, lov;
        #pragma unroll
        for (int s = 0; s < 8; ++s) {
            int i = i0 + s;
            float v = 0.f;
            if (i < 49) v = fs[(75 + i) * 200 + j] * xpat[i][j >> 2] * inv_s[i];
            _Float16 hi = (_Float16)v;
            hiv[s] = hi;
            lov[s] = (_Float16)(v - (float)hi);
        }
        _Float16* B2h = (_Float16*)R1;
        const int base0 = ((tn * 8 + ksq) * 64 + l) * 8;
        *(h8*)(B2h + base0) = hiv;
        *(h8*)(B2h + base0 + 2048) = lov;
    }
    __syncthreads();

    // P2: ph2 MFMA D[128][64] = c_hi @ (T_hi + T_lo), 8 K-steps, dual acc;
    // epilogue scatters D*wn (hi f16 only) into padded A3 frag layout
    {
        const int tm = swid >> 1, tn = swid & 1;
        f32x16 acc0, acc1;
        #pragma unroll
        for (int i = 0; i < 16; ++i) { acc0[i] = 0.f; acc1[i] = 0.f; }
        const h8* wsA2 = (const h8*)(ws + WS_A2);
        #pragma unroll
        for (int kq = 0; kq < 4; ++kq) {
            h8 a   = wsA2[(tm * 4 + kq) * 64 + lane];
            h8 bhi = *(const h8*)(R1 + (((tn * 8 + kq) * 64 + lane) << 4));
            h8 blo = *(const h8*)(R1 + (((tn * 8 + kq + 4) * 64 + lane) << 4));
            acc0 = __builtin_amdgcn_mfma_f32_32x32x16_f16(a, bhi, acc0, 0, 0, 0);
            acc1 = __builtin_amdgcn_mfma_f32_32x32x16_f16(a, blo, acc1, 0, 0, 0);
        }
        f32x16 acc = acc0 + acc1;
        const float* wn = ws + WS_WN;
        const int j = (lane & 31) + 32 * tn;
        const int q = j >> 2;
        _Float16* A3h = (_Float16*)R2;
        #pragma unroll
        for (int r = 0; r < 16; ++r) {
            int row = (r & 3) + 8 * (r >> 2) + 4 * (lane >> 5) + 32 * tm;
            if (row < 100) {
                int m = (row < 50) ? row : row - 50;
                float v = acc[r] * wn[m * 16 + q];
                int kap = j + ((row < 50) ? 0 : 64);
                int tm3 = m >> 5;
                int pks = kap >> 4;                    // 0..7
                int bb = (kap >> 3) & 1;
                int elem = ((tm3 * 8 + pks) * 65 + (m & 31) + 33 * bb) * 8 + (kap & 7);
                A3h[elem] = (_Float16)v;
            }
        }
    }
    __syncthreads();

    // P3: ph3 MFMA G'[64][128] = O_hi @ (B_hi + B_lo), 16 K-steps, dual acc;
    // epilogue fuses |G| via adjacent-lane shfl -> absG (overlays R1)
    {
        const int tm3 = swid >> 2, tn3 = swid & 3;
        f32x16 acc0, acc1;
        #pragma unroll
        for (int i = 0; i < 16; ++i) { acc0[i] = 0.f; acc1[i] = 0.f; }
        const h8* wsB3 = (const h8*)(ws + WS_B3);
        const int aoff = lane + (lane >> 5);           // padded read index
        #pragma unroll
        for (int kq = 0; kq < 8; ++kq) {
            h8 a   = *(const h8*)(R2 + (((tm3 * 8 + kq) * 65 + aoff) << 4));
            h8 bhi = wsB3[(tn3 * 16 + kq) * 64 + lane];
            h8 blo = wsB3[(tn3 * 16 + kq + 8) * 64 + lane];
            acc0 = __builtin_amdgcn_mfma_f32_32x32x16_f16(a, bhi, acc0, 0, 0, 0);
            acc1 = __builtin_amdgcn_mfma_f32_32x32x16_f16(a, blo, acc1, 0, 0, 0);
        }
        f32x16 acc = acc0 + acc1;
        const int np = (lane & 31) + 32 * tn3;
        float* aG = (float*)R1;
        if (np < 104) {
            const int cc = np >> 1;
            const bool wr = !(np & 1);
            #pragma unroll
            for (int r = 0; r < 16; ++r) {
                int row = (r & 3) + 8 * (r >> 2) + 4 * (lane >> 5) + 32 * tm3;
                float g = acc[r];
                float gp = __shfl_xor(g, 1);
                if (row < 50 && wr) aG[row * 52 + cc] = sqrtf(g * g + gp * gp);
            }
        }
    }
    __syncthreads();

    // P4: pool absG (2x3/2x1); r = v * min(rcp-amp window)
    const float* ra = ws + WS_RCPA;
    const float* aG = (const float*)R1;
    float local = 0.f;
    for (int o = t; o < 1300; o += 512) {
        int hh = o / 50, w2 = o - hh * 50;
        int h = hh + 12;
        int m1 = 2 * h - 25, m2 = m1 + 1;
        float v = 0.f;
        #pragma unroll
        for (int du = 0; du < 3; ++du) {
            int u = w2 + du;
            if (m1 >= 0) v = fmaxf(v, aG[m1 * 52 + u]);
            if (m2 < 50) v = fmaxf(v, aG[m2 * 52 + u]);
        }
        float rc = ra[(2 * h) * 52 + w2];
        #pragma unroll
        for (int du = 1; du < 3; ++du) rc = fminf(rc, ra[(2 * h) * 52 + w2 + du]);
        #pragma unroll
        for (int du = 0; du < 3; ++du) rc = fminf(rc, ra[(2 * h + 1) * 52 + w2 + du]);
        float r = v * rc;
        res_s[hh][w2] = r;
        local = fmaxf(local, r);
    }
    #pragma unroll
    for (int off = 32; off > 0; off >>= 1)
        local = fmaxf(local, __shfl_xor(local, off));
    if (lane == 0) red8[wid] = local;
    __syncthreads();

    float mres;
    {
        float4 r0 = *(const float4*)&red8[0];
        float4 r1 = *(const float4*)&red8[4];
        float m0 = fmaxf(fmaxf(r0.x, r0.y), fmaxf(r0.z, r0.w));
        float m1 = fmaxf(fmaxf(r1.x, r1.y), fmaxf(r1.z, r1.w));
        mres = fmaxf(m0, m1);
    }
    float invm = 1.f / (mres + EPS);

    // P5: out[b,r,c] = bias[r,c] + res[c,r]*invm * imax[r]*wmax[c]
    const float* wmaxg = ws + WS_WMAX;
    for (int o = t; o < 2450; o += 512) {
        int r = o / 50, c = o - r * 50;
        float val = bias[o];
        if (c >= 12 && c < 38)
            val = fmaf(res_s[c - 12][r] * invm, imax_s[r] * wmaxg[c], val);
        out[b * 2450 + o] = val;
    }
}

extern "C" void kernel_launch(void* const* d_in, const int* in_sizes, int n_in,
                              void* d_out, int out_size, void* d_ws, size_t ws_size,
                              hipStream_t stream) {
    const float* in   = (const float*)d_in[0];   // [512,1,28,28]
    const float* w    = (const float*)d_in[1];   // [50,16]
    const float* bias = (const float*)d_in[2];   // [1,49,50]
    const float* fs   = (const float*)d_in[3];   // [200,200]
    float* out = (float*)d_out;                  // [512,49,50] f32
    float* ws  = (float*)d_ws;

    hipLaunchKernelGGL(k_prelude, dim3(195),  dim3(256), 0, stream, w, fs, ws);
    hipLaunchKernelGGL(k_main,    dim3(512),  dim3(512), 0, stream, in, bias, fs, ws, out);
}

// Round 13
// 24.251 us; speedup vs baseline: 5.9980x; 1.0231x over previous
//
#include <hip/hip_runtime.h>
#include <math.h>

#define EPS 1e-8f
#define TWOPI 6.2831853071795864769f

typedef _Float16 h8 __attribute__((ext_vector_type(8)));
typedef float f32x16 __attribute__((ext_vector_type(16)));

// ws layout (float offsets)
#define WS_WMAX 0        // 50
#define WS_WN   64       // 800
#define WS_RCPA 1024     // 5200: reciprocal of |fft_sig| window
#define WS_A2   8192     // f16 frags [4 tm][4 pks][64 l][8 s] = 8192 f16 (hi only)
#define WS_B3   16384    // f16 frags [4 tn][16 pks][64 l][8 s] = 32768 f16 (hi+lo, interleaved cols)

// Shared A/B fragment k-map (identical for builders & consumers):
//   row/col = 32*tile + (l&31);  k = 16*ks + 8*(l>>5) + s

// ---- prologue: amp (blocks 0..162) + tables/fragments (163..194) -----------
__global__ __launch_bounds__(256) void k_prelude(const float* __restrict__ w,
                                                 const float* __restrict__ fs,
                                                 float* __restrict__ ws) {
    const int blk = blockIdx.x, t = threadIdx.x;
    if (blk < 163) {
        __shared__ float tc[200], tsn[200];
        for (int i = t; i < 200; i += 256) {
            float s, c;
            sincosf(-TWOPI * (float)i / 200.f, &s, &c);
            tc[i] = c; tsn[i] = s;
        }
        __syncthreads();
        int gid = blk * 256 + t;
        int q = gid >> 3, part = gid & 7;
        float aR = 0.f, aI = 0.f;
        if (q < 5200) {
            int s_ = q / 52, u = q - s_ * 52;
            int k = (150 + s_) % 200;
            int j = 101 + u;
            int ph = (k * (part * 25)) % 200;
            for (int r = part * 25; r < part * 25 + 25; ++r) {
                float v = fs[r * 200 + j];
                aR = fmaf(v, tc[ph], aR);
                aI = fmaf(v, tsn[ph], aI);
                ph += k; if (ph >= 200) ph -= 200;
            }
        }
        aR += __shfl_xor(aR, 1); aI += __shfl_xor(aI, 1);
        aR += __shfl_xor(aR, 2); aI += __shfl_xor(aI, 2);
        aR += __shfl_xor(aR, 4); aI += __shfl_xor(aI, 4);
        if (q < 5200 && part == 0)
            ws[WS_RCPA + q] = 1.0f / sqrtf(aR * aR + aI * aI);
    } else {
        int gid = (blk - 163) * 256 + t;   // 0..8191
        if (gid < 50) {
            float mx = 0.f, vals[16];
            for (int q = 0; q < 16; ++q) {
                float v = fabsf(w[gid * 16 + q]);
                vals[q] = v; mx = fmaxf(mx, v);
            }
            ws[WS_WMAX + gid] = mx;
            float d = mx + EPS;
            for (int q = 0; q < 16; ++q) ws[WS_WN + gid * 16 + q] = vals[q] / d;
        }
        // A2 (hi only) = [cR(50); cI(50); 0] rows x k(0..48)
        {
            _Float16* A2h = (_Float16*)(ws + WS_A2);
            int a = gid;   // exactly 8192 threads
            int s = a & 7, l = (a >> 3) & 63, pks = (a >> 9) & 3, tm = a >> 11;
            int row = 32 * tm + (l & 31);
            int k = 16 * pks + 8 * (l >> 5) + s;
            float X = 0.f;
            if (row < 100 && k < 49) {
                int m = (row < 50) ? row : row - 50;
                int kk = (175 + m) % 200;
                int ph = (kk * (75 + k)) % 200;
                float sn, cs;
                sincosf(-TWOPI * (float)ph / 200.f, &sn, &cs);
                X = (row < 50) ? cs : sn;
            }
            A2h[a] = (_Float16)X;
        }
        // B3 INTERLEAVED: col n' = 2*cc + isI (0..103)
        //   isI=0: kap<64 ? eR : -eI ;  isI=1: kap<64 ? eI : eR
        _Float16* B3h = (_Float16*)(ws + WS_B3);
        for (int bI = gid; bI < 32768; bI += 8192) {
            int s = bI & 7, l = (bI >> 3) & 63, pks = (bI >> 9) & 15, tn = bI >> 13;
            int part = pks >> 3;
            int np = 32 * tn + (l & 31);
            int kap = 16 * (pks & 7) + 8 * (l >> 5) + s;
            float X = 0.f;
            if (np < 104) {
                int cc = np >> 1;
                int j = kap & 63;
                int ph = ((cc + 1) * j) % 200;
                float sn, cs;
                sincosf(-TWOPI * (float)ph / 200.f, &sn, &cs);
                X = (np & 1) ? ((kap < 64) ? sn : cs) : ((kap < 64) ? cs : -sn);
            }
            _Float16 hi = (_Float16)X;
            B3h[bI] = part ? (_Float16)(X - (float)hi) : hi;
        }
    }
}

// -------- main batched kernel: one block (512 thr = 8 waves) per batch ------
// __launch_bounds__(512, 6): 6 waves/SIMD -> 3 blocks/CU (LDS 42KB x3 = 126KB)
__global__ __launch_bounds__(512, 6) void k_main(const float* __restrict__ in,
                                                 const float* __restrict__ bias,
                                                 const float* __restrict__ fs,
                                                 const float* __restrict__ ws,
                                                 float* __restrict__ out) {
    __shared__ __align__(16) char R1[16384];   // B2 frags; later absG f32[2600]
    __shared__ __align__(16) char R2[16640];   // A3 hi frags [2 tm3][8 pks][65 slots][8 s] f16
    __shared__ float xpat[50][16];
    __shared__ float imax_s[50];
    __shared__ float inv_s[50];
    __shared__ float res_s[26][50];
    __shared__ __align__(16) float red8[8];

    const int t = threadIdx.x;
    const int b = blockIdx.x;
    const int lane = t & 63;
    const int wid = t >> 6;                               // 0..7
    const int swid = __builtin_amdgcn_readfirstlane(wid);
    const float* ib = in + b * 784;

    // P1-prefetch: fs values for this thread's B2 fragment (independent of P0)
    const int p1_l = t & 63;
    const int p1_ksq = (t >> 6) & 3;
    const int p1_tn = t >> 8;                 // 0..1
    const int p1_j = (p1_l & 31) + 32 * p1_tn;
    const int p1_i0 = 16 * p1_ksq + 8 * (p1_l >> 5);
    float fsv[8];
    #pragma unroll
    for (int s = 0; s < 8; ++s) {
        int i = p1_i0 + s;
        fsv[s] = (i < 49) ? fs[(75 + i) * 200 + p1_j] : 0.f;
    }

    // P0: patches (float4) + per-row max via quad shuffle
    if (t < 196) {
        int row = t >> 2, s4 = t & 3;
        int pr = row / 7, pc = row - pr * 7;
        float4 v4 = *(const float4*)(ib + (pr * 4 + s4) * 28 + pc * 4);
        *(float4*)(&xpat[row][s4 * 4]) = v4;
        float mx = fmaxf(fmaxf(v4.x, v4.y), fmaxf(v4.z, v4.w));
        mx = fmaxf(mx, __shfl_xor(mx, 1));
        mx = fmaxf(mx, __shfl_xor(mx, 2));
        if (s4 == 0) { imax_s[row] = mx; inv_s[row] = 1.f / (mx + EPS); }
    }
    // zero R2 (stale-LDS insurance for unwritten m>=50 slots)
    {
        h8 z;
        #pragma unroll
        for (int s = 0; s < 8; ++s) z[s] = (_Float16)0.f;
        for (int o = t; o < 1040; o += 512) *(h8*)(R2 + (o << 4)) = z;
    }
    __syncthreads();

    // P1: B2 frags from prefetched fs; two ds_write_b128 per thread
    {
        h8 hiv, lov;
        #pragma unroll
        for (int s = 0; s < 8; ++s) {
            int i = p1_i0 + s;
            float v = 0.f;
            if (i < 49) v = fsv[s] * xpat[i][p1_j >> 2] * inv_s[i];
            _Float16 hi = (_Float16)v;
            hiv[s] = hi;
            lov[s] = (_Float16)(v - (float)hi);
        }
        _Float16* B2h = (_Float16*)R1;
        const int base0 = ((p1_tn * 8 + p1_ksq) * 64 + p1_l) * 8;
        *(h8*)(B2h + base0) = hiv;
        *(h8*)(B2h + base0 + 2048) = lov;
    }
    __syncthreads();

    // P2: ph2 MFMA D[128][64] = c_hi @ (T_hi + T_lo), 8 K-steps, dual acc;
    // epilogue scatters D*wn (hi f16 only) into padded A3 frag layout
    {
        const int tm = swid >> 1, tn = swid & 1;
        f32x16 acc0, acc1;
        #pragma unroll
        for (int i = 0; i < 16; ++i) { acc0[i] = 0.f; acc1[i] = 0.f; }
        const h8* wsA2 = (const h8*)(ws + WS_A2);
        #pragma unroll
        for (int kq = 0; kq < 4; ++kq) {
            h8 a   = wsA2[(tm * 4 + kq) * 64 + lane];
            h8 bhi = *(const h8*)(R1 + (((tn * 8 + kq) * 64 + lane) << 4));
            h8 blo = *(const h8*)(R1 + (((tn * 8 + kq + 4) * 64 + lane) << 4));
            acc0 = __builtin_amdgcn_mfma_f32_32x32x16_f16(a, bhi, acc0, 0, 0, 0);
            acc1 = __builtin_amdgcn_mfma_f32_32x32x16_f16(a, blo, acc1, 0, 0, 0);
        }
        f32x16 acc = acc0 + acc1;
        const float* wn = ws + WS_WN;
        const int j = (lane & 31) + 32 * tn;
        const int q = j >> 2;
        _Float16* A3h = (_Float16*)R2;
        #pragma unroll
        for (int r = 0; r < 16; ++r) {
            int row = (r & 3) + 8 * (r >> 2) + 4 * (lane >> 5) + 32 * tm;
            if (row < 100) {
                int m = (row < 50) ? row : row - 50;
                float v = acc[r] * wn[m * 16 + q];
                int kap = j + ((row < 50) ? 0 : 64);
                int tm3 = m >> 5;
                int pks = kap >> 4;                    // 0..7
                int bb = (kap >> 3) & 1;
                int elem = ((tm3 * 8 + pks) * 65 + (m & 31) + 33 * bb) * 8 + (kap & 7);
                A3h[elem] = (_Float16)v;
            }
        }
    }
    __syncthreads();

    // P3: ph3 MFMA G'[64][128] = O_hi @ (B_hi + B_lo), 16 K-steps, dual acc;
    // epilogue fuses |G| via adjacent-lane shfl -> absG (overlays R1)
    {
        const int tm3 = swid >> 2, tn3 = swid & 3;
        f32x16 acc0, acc1;
        #pragma unroll
        for (int i = 0; i < 16; ++i) { acc0[i] = 0.f; acc1[i] = 0.f; }
        const h8* wsB3 = (const h8*)(ws + WS_B3);
        const int aoff = lane + (lane >> 5);           // padded read index
        #pragma unroll
        for (int kq = 0; kq < 8; ++kq) {
            h8 a   = *(const h8*)(R2 + (((tm3 * 8 + kq) * 65 + aoff) << 4));
            h8 bhi = wsB3[(tn3 * 16 + kq) * 64 + lane];
            h8 blo = wsB3[(tn3 * 16 + kq + 8) * 64 + lane];
            acc0 = __builtin_amdgcn_mfma_f32_32x32x16_f16(a, bhi, acc0, 0, 0, 0);
            acc1 = __builtin_amdgcn_mfma_f32_32x32x16_f16(a, blo, acc1, 0, 0, 0);
        }
        f32x16 acc = acc0 + acc1;
        const int np = (lane & 31) + 32 * tn3;
        float* aG = (float*)R1;
        if (np < 104) {
            const int cc = np >> 1;
            const bool wr = !(np & 1);
            #pragma unroll
            for (int r = 0; r < 16; ++r) {
                int row = (r & 3) + 8 * (r >> 2) + 4 * (lane >> 5) + 32 * tm3;
                float g = acc[r];
                float gp = __shfl_xor(g, 1);
                if (row < 50 && wr) aG[row * 52 + cc] = sqrtf(g * g + gp * gp);
            }
        }
    }
    __syncthreads();

    // P4: pool absG (2x3/2x1); r = v * min(rcp-amp window)
    const float* ra = ws + WS_RCPA;
    const float* aG = (const float*)R1;
    float local = 0.f;
    for (int o = t; o < 1300; o += 512) {
        int hh = o / 50, w2 = o - hh * 50;
        int h = hh + 12;
        int m1 = 2 * h - 25, m2 = m1 + 1;
        float v = 0.f;
        #pragma unroll
        for (int du = 0; du < 3; ++du) {
            int u = w2 + du;
            if (m1 >= 0) v = fmaxf(v, aG[m1 * 52 + u]);
            if (m2 < 50) v = fmaxf(v, aG[m2 * 52 + u]);
        }
        float rc = ra[(2 * h) * 52 + w2];
        #pragma unroll
        for (int du = 1; du < 3; ++du) rc = fminf(rc, ra[(2 * h) * 52 + w2 + du]);
        #pragma unroll
        for (int du = 0; du < 3; ++du) rc = fminf(rc, ra[(2 * h + 1) * 52 + w2 + du]);
        float r = v * rc;
        res_s[hh][w2] = r;
        local = fmaxf(local, r);
    }
    #pragma unroll
    for (int off = 32; off > 0; off >>= 1)
        local = fmaxf(local, __shfl_xor(local, off));
    if (lane == 0) red8[wid] = local;
    __syncthreads();

    float mres;
    {
        float4 r0 = *(const float4*)&red8[0];
        float4 r1 = *(const float4*)&red8[4];
        float m0 = fmaxf(fmaxf(r0.x, r0.y), fmaxf(r0.z, r0.w));
        float m1 = fmaxf(fmaxf(r1.x, r1.y), fmaxf(r1.z, r1.w));
        mres = fmaxf(m0, m1);
    }
    float invm = 1.f / (mres + EPS);

    // P5: out[b,r,c] = bias[r,c] + res[c,r]*invm * imax[r]*wmax[c]
    const float* wmaxg = ws + WS_WMAX;
    for (int o = t; o < 2450; o += 512) {
        int r = o / 50, c = o - r * 50;
        float val = bias[o];
        if (c >= 12 && c < 38)
            val = fmaf(res_s[c - 12][r] * invm, imax_s[r] * wmaxg[c], val);
        out[b * 2450 + o] = val;
    }
}

extern "C" void kernel_launch(void* const* d_in, const int* in_sizes, int n_in,
                              void* d_out, int out_size, void* d_ws, size_t ws_size,
                              hipStream_t stream) {
    const float* in   = (const float*)d_in[0];   // [512,1,28,28]
    const float* w    = (const float*)d_in[1];   // [50,16]
    const float* bias = (const float*)d_in[2];   // [1,49,50]
    const float* fs   = (const float*)d_in[3];   // [200,200]
    float* out = (float*)d_out;                  // [512,49,50] f32
    float* ws  = (float*)d_ws;

    hipLaunchKernelGGL(k_prelude, dim3(195),  dim3(256), 0, stream, w, fs, ws);
    hipLaunchKernelGGL(k_main,    dim3(512),  dim3(512), 0, stream, in, bias, fs, ws, out);
}